// Round 1
// baseline (781.583 us; speedup 1.0000x reference)
//
#include <hip/hip_runtime.h>
#include <hip/hip_bf16.h>
#include <math.h>

// ---------------------------------------------------------------------------
// GAT 2-layer forward. N=50000 nodes, E=800000 edges, 256 in-feats,
// layer1: 8 heads x 64, layer2: 1 head x 64. All fp32.
//
// Pipeline:
//   CSR build (dst-sorted edge list, shared by both layers)
//   h1 = feats @ W1                      (fp32 tiled GEMM, 128x128x16)
//   el1/er1 = head-wise dots of h1 with attn vectors
//   agg1: per-dst online-softmax over incoming edges + weighted gather-sum
//         of h1[src]; + b1; relu  -> x2 [N,512]
//   h2 = x2 @ W2                          (fp32 tiled GEMM, 128x64x16)
//   el2/er2
//   agg2: same with 1 head -> d_out [N,64] (+ b2)
// ---------------------------------------------------------------------------

#define NEG_SLOPE 0.2f

__device__ __forceinline__ float lrelu(float x) { return x >= 0.f ? x : NEG_SLOPE * x; }

__device__ __forceinline__ float wred_max(float v) {
  #pragma unroll
  for (int off = 32; off; off >>= 1) v = fmaxf(v, __shfl_xor(v, off));
  return v;
}
__device__ __forceinline__ float wred_sum(float v) {
  #pragma unroll
  for (int off = 32; off; off >>= 1) v += __shfl_xor(v, off);
  return v;
}

// ---------------------------- CSR build ------------------------------------

__global__ __launch_bounds__(256) void hist_k(const int* __restrict__ dst, int* __restrict__ deg, int E) {
  int e = blockIdx.x * 256 + threadIdx.x;
  if (e < E) atomicAdd(&deg[dst[e]], 1);
}

__global__ __launch_bounds__(1024) void scan_block_k(const int* __restrict__ deg,
                                                     int* __restrict__ row_ptr,  // writes row_ptr[1+i]
                                                     int* __restrict__ bsum, int n) {
  __shared__ int sm[1024];
  int i = blockIdx.x * 1024 + threadIdx.x;
  int v = (i < n) ? deg[i] : 0;
  sm[threadIdx.x] = v;
  __syncthreads();
  for (int off = 1; off < 1024; off <<= 1) {
    int t = (threadIdx.x >= off) ? sm[threadIdx.x - off] : 0;
    __syncthreads();
    sm[threadIdx.x] += t;
    __syncthreads();
  }
  if (i < n) row_ptr[1 + i] = sm[threadIdx.x];
  if (threadIdx.x == 1023) bsum[blockIdx.x] = sm[1023];
}

__global__ void scan_sums_k(int* bsum, int nb) {
  if (threadIdx.x == 0 && blockIdx.x == 0) {
    int run = 0;
    for (int i = 0; i < nb; ++i) { int t = bsum[i]; bsum[i] = run; run += t; }
  }
}

__global__ __launch_bounds__(256) void scan_add_k(int* __restrict__ row_ptr, const int* __restrict__ bsum, int n) {
  int i = blockIdx.x * 256 + threadIdx.x;
  if (i < n) row_ptr[1 + i] += bsum[i / 1024];
  if (i == 0) row_ptr[0] = 0;
}

__global__ __launch_bounds__(256) void pos_init_k(int* __restrict__ pos, const int* __restrict__ row_ptr, int n) {
  int i = blockIdx.x * 256 + threadIdx.x;
  if (i < n) pos[i] = row_ptr[i];
}

__global__ __launch_bounds__(256) void scatter_k(const int* __restrict__ src, const int* __restrict__ dst,
                                                 int* __restrict__ pos, int* __restrict__ esrc, int E) {
  int e = blockIdx.x * 256 + threadIdx.x;
  if (e < E) {
    int slot = atomicAdd(&pos[dst[e]], 1);
    esrc[slot] = src[e];
  }
}

// ---------------------------- fp32 GEMM ------------------------------------
// C[M,N] = A[M,K] @ B[K,N]; BM=128, BK=16, TM=8; BN/TN template.
// Requires K % 16 == 0 and N % BN == 0 (true for both uses).

template <int BN, int TN>
__global__ __launch_bounds__(256) void gemm_f32_k(const float* __restrict__ A,
                                                  const float* __restrict__ B,
                                                  float* __restrict__ C,
                                                  int M, int N, int K) {
  constexpr int BM = 128, BK = 16, TM = 8;
  __shared__ float As[BK][BM + 4];   // +4 pad keeps f4 alignment, reduces store conflicts
  __shared__ float Bs[BK][BN];
  const int tid = threadIdx.x;
  const int tx = tid & 15;           // 16 col groups
  const int ty = tid >> 4;           // 16 row groups
  const int row0 = blockIdx.x * BM;
  const int col0 = blockIdx.y * BN;

  float acc[TM][TN];
  #pragma unroll
  for (int i = 0; i < TM; ++i)
    #pragma unroll
    for (int j = 0; j < TN; ++j) acc[i][j] = 0.f;

  for (int k0 = 0; k0 < K; k0 += BK) {
    // A tile: BM*BK floats = 512 float4, transposed into As[k][m]
    #pragma unroll
    for (int it = 0; it < (BM * BK / 4) / 256; ++it) {
      int f4 = tid + it * 256;
      int row = f4 >> 2;             // BK/4 = 4 f4 per row
      int c4 = f4 & 3;
      int grow = row0 + row;
      float4 v = make_float4(0.f, 0.f, 0.f, 0.f);
      if (grow < M) v = *(const float4*)(A + (size_t)grow * K + k0 + c4 * 4);
      As[c4 * 4 + 0][row] = v.x;
      As[c4 * 4 + 1][row] = v.y;
      As[c4 * 4 + 2][row] = v.z;
      As[c4 * 4 + 3][row] = v.w;
    }
    // B tile: BK*BN floats
    #pragma unroll
    for (int it = 0; it < (BK * BN / 4) / 256; ++it) {
      int f4 = tid + it * 256;
      int kk = f4 / (BN / 4);
      int n4 = f4 % (BN / 4);
      *(float4*)&Bs[kk][n4 * 4] = *(const float4*)(B + (size_t)(k0 + kk) * N + col0 + n4 * 4);
    }
    __syncthreads();
    #pragma unroll
    for (int kk = 0; kk < BK; ++kk) {
      float a[TM], b[TN];
      float4 a0 = *(const float4*)&As[kk][ty * TM];
      float4 a1 = *(const float4*)&As[kk][ty * TM + 4];
      a[0] = a0.x; a[1] = a0.y; a[2] = a0.z; a[3] = a0.w;
      a[4] = a1.x; a[5] = a1.y; a[6] = a1.z; a[7] = a1.w;
      #pragma unroll
      for (int j = 0; j < TN; j += 4) {
        float4 bv = *(const float4*)&Bs[kk][tx * TN + j];
        b[j] = bv.x; b[j + 1] = bv.y; b[j + 2] = bv.z; b[j + 3] = bv.w;
      }
      #pragma unroll
      for (int i = 0; i < TM; ++i)
        #pragma unroll
        for (int j = 0; j < TN; ++j) acc[i][j] = fmaf(a[i], b[j], acc[i][j]);
    }
    __syncthreads();
  }
  #pragma unroll
  for (int i = 0; i < TM; ++i) {
    int grow = row0 + ty * TM + i;
    if (grow < M) {
      #pragma unroll
      for (int j = 0; j < TN; j += 4) {
        float4 v = make_float4(acc[i][j], acc[i][j + 1], acc[i][j + 2], acc[i][j + 3]);
        *(float4*)(C + (size_t)grow * N + col0 + tx * TN + j) = v;
      }
    }
  }
}

// ------------------------- attention dot products --------------------------

// layer1: el[n,h] = sum_d h1[n,h*64+d]*attn_l[h,d]; one wave per node
__global__ __launch_bounds__(256) void elr1_k(const float* __restrict__ h1,
                                              const float* __restrict__ al,
                                              const float* __restrict__ ar,
                                              float* __restrict__ el, float* __restrict__ er, int N) {
  int wave = blockIdx.x * 4 + (threadIdx.x >> 6);
  int lane = threadIdx.x & 63;
  if (wave >= N) return;
  float alv[8], arv[8];
  #pragma unroll
  for (int h = 0; h < 8; ++h) { alv[h] = al[h * 64 + lane]; arv[h] = ar[h * 64 + lane]; }
  const float* hr = h1 + (size_t)wave * 512 + lane;
  float se[8], sr[8];
  #pragma unroll
  for (int h = 0; h < 8; ++h) {
    float v = hr[h * 64];
    se[h] = v * alv[h];
    sr[h] = v * arv[h];
  }
  #pragma unroll
  for (int off = 32; off; off >>= 1) {
    #pragma unroll
    for (int h = 0; h < 8; ++h) {
      se[h] += __shfl_xor(se[h], off);
      sr[h] += __shfl_xor(sr[h], off);
    }
  }
  if (lane == 0) {
    #pragma unroll
    for (int h = 0; h < 8; ++h) {
      el[(size_t)wave * 8 + h] = se[h];
      er[(size_t)wave * 8 + h] = sr[h];
    }
  }
}

// layer2 (1 head, D=64): one wave per node
__global__ __launch_bounds__(256) void elr2_k(const float* __restrict__ h2,
                                              const float* __restrict__ al,
                                              const float* __restrict__ ar,
                                              float* __restrict__ el, float* __restrict__ er, int N) {
  int wave = blockIdx.x * 4 + (threadIdx.x >> 6);
  int lane = threadIdx.x & 63;
  if (wave >= N) return;
  float v = h2[(size_t)wave * 64 + lane];
  float sl = v * al[lane];
  float sr = v * ar[lane];
  sl = wred_sum(sl);
  sr = wred_sum(sr);
  if (lane == 0) { el[wave] = sl; er[wave] = sr; }
}

// ------------------------- aggregation (edge softmax + SpMM) ----------------

// layer1: 8 heads x 64 dims. One wave per dst node; lane l owns dims {h*64+l}.
// Online softmax over incoming-edge batches of 64.
__global__ __launch_bounds__(256) void agg1_k(const float* __restrict__ h1,
                                              const float* __restrict__ el,
                                              const float* __restrict__ er,
                                              const int* __restrict__ row_ptr,
                                              const int* __restrict__ esrc,
                                              const float* __restrict__ b1,
                                              float* __restrict__ x2, int N) {
  int n = blockIdx.x * 4 + (threadIdx.x >> 6);
  int lane = threadIdx.x & 63;
  if (n >= N) return;
  int start = row_ptr[n], end = row_ptr[n + 1];

  float er8[8];
  #pragma unroll
  for (int h = 0; h < 8; ++h) er8[h] = er[(size_t)n * 8 + h];

  float acc[8], m[8], denom[8];
  #pragma unroll
  for (int h = 0; h < 8; ++h) { acc[h] = 0.f; m[h] = -INFINITY; denom[h] = 0.f; }

  for (int base = start; base < end; base += 64) {
    int j = base + lane;
    bool valid = j < end;
    int s = valid ? esrc[j] : 0;

    float4 e0 = *(const float4*)(el + (size_t)s * 8);
    float4 e1 = *(const float4*)(el + (size_t)s * 8 + 4);
    float sc[8];
    sc[0] = lrelu(e0.x + er8[0]); sc[1] = lrelu(e0.y + er8[1]);
    sc[2] = lrelu(e0.z + er8[2]); sc[3] = lrelu(e0.w + er8[3]);
    sc[4] = lrelu(e1.x + er8[4]); sc[5] = lrelu(e1.y + er8[5]);
    sc[6] = lrelu(e1.z + er8[6]); sc[7] = lrelu(e1.w + er8[7]);
    if (!valid) {
      #pragma unroll
      for (int h = 0; h < 8; ++h) sc[h] = -INFINITY;
    }

    float p[8];
    #pragma unroll
    for (int h = 0; h < 8; ++h) {
      float bm = wred_max(sc[h]);
      float nm = fmaxf(m[h], bm);
      float f = expf(m[h] - nm);   // 0 if m was -inf
      m[h] = nm;
      p[h] = valid ? expf(sc[h] - nm) : 0.f;
      denom[h] = denom[h] * f + wred_sum(p[h]);
      acc[h] *= f;
    }

    int cnt = min(64, end - base);
    for (int jj = 0; jj < cnt; ++jj) {
      int ss = __shfl(s, jj);
      const float* hr = h1 + (size_t)ss * 512 + lane;
      #pragma unroll
      for (int h = 0; h < 8; ++h) {
        float a = __shfl(p[h], jj);
        acc[h] = fmaf(a, hr[h * 64], acc[h]);
      }
    }
  }

  int deg = end - start;
  #pragma unroll
  for (int h = 0; h < 8; ++h) {
    float v = deg ? acc[h] / denom[h] : 0.f;
    v += b1[h * 64 + lane];
    v = fmaxf(v, 0.f);  // relu between layers, fused
    x2[(size_t)n * 512 + h * 64 + lane] = v;
  }
}

// layer2: 1 head x 64 dims; writes final output (+b2, mean over 1 head = id)
__global__ __launch_bounds__(256) void agg2_k(const float* __restrict__ h2,
                                              const float* __restrict__ el,
                                              const float* __restrict__ er,
                                              const int* __restrict__ row_ptr,
                                              const int* __restrict__ esrc,
                                              const float* __restrict__ b2,
                                              float* __restrict__ out, int N) {
  int n = blockIdx.x * 4 + (threadIdx.x >> 6);
  int lane = threadIdx.x & 63;
  if (n >= N) return;
  int start = row_ptr[n], end = row_ptr[n + 1];
  float ern = er[n];
  float acc = 0.f, m = -INFINITY, denom = 0.f;

  for (int base = start; base < end; base += 64) {
    int j = base + lane;
    bool valid = j < end;
    int s = valid ? esrc[j] : 0;
    float sc = valid ? lrelu(el[s] + ern) : -INFINITY;
    float bm = wred_max(sc);
    float nm = fmaxf(m, bm);
    float f = expf(m - nm);
    m = nm;
    float p = valid ? expf(sc - nm) : 0.f;
    denom = denom * f + wred_sum(p);
    acc *= f;
    int cnt = min(64, end - base);
    for (int jj = 0; jj < cnt; ++jj) {
      int ss = __shfl(s, jj);
      float a = __shfl(p, jj);
      acc = fmaf(a, h2[(size_t)ss * 64 + lane], acc);
    }
  }
  int deg = end - start;
  float v = deg ? acc / denom : 0.f;
  out[(size_t)n * 64 + lane] = v + b2[lane];
}

// ---------------------------------------------------------------------------

extern "C" void kernel_launch(void* const* d_in, const int* in_sizes, int n_in,
                              void* d_out, int out_size, void* d_ws, size_t ws_size,
                              hipStream_t stream) {
  const float* feats = (const float*)d_in[0];
  const float* W1    = (const float*)d_in[1];
  const float* al1   = (const float*)d_in[2];
  const float* ar1   = (const float*)d_in[3];
  const float* b1    = (const float*)d_in[4];
  const float* W2    = (const float*)d_in[5];
  const float* al2   = (const float*)d_in[6];
  const float* ar2   = (const float*)d_in[7];
  const float* b2    = (const float*)d_in[8];
  const int*   src   = (const int*)d_in[9];
  const int*   dst   = (const int*)d_in[10];

  const int N = in_sizes[0] / 256;   // 50000
  const int E = in_sizes[9];         // 800000
  const int IN = 256, HD1 = 512, D2 = 64;

  // workspace layout
  char* w = (char*)d_ws;
  size_t off = 0;
  auto alloc = [&](size_t bytes) -> void* {
    void* p = w + off;
    off = (off + bytes + 255) & ~(size_t)255;
    return p;
  };
  float* h1      = (float*)alloc((size_t)N * HD1 * 4);
  float* x2      = (float*)alloc((size_t)N * HD1 * 4);
  float* h2      = (float*)alloc((size_t)N * D2 * 4);
  float* el1     = (float*)alloc((size_t)N * 8 * 4);
  float* er1     = (float*)alloc((size_t)N * 8 * 4);
  float* el2     = (float*)alloc((size_t)N * 4);
  float* er2     = (float*)alloc((size_t)N * 4);
  int*   deg     = (int*)alloc((size_t)N * 4);
  int*   row_ptr = (int*)alloc((size_t)(N + 1) * 4);
  int*   pos     = (int*)alloc((size_t)N * 4);
  int*   bsum    = (int*)alloc(64 * 4);
  int*   esrc    = (int*)alloc((size_t)E * 4);

  float* outp = (float*)d_out;

  const int NB_E   = (E + 255) / 256;
  const int NB_N   = (N + 255) / 256;
  const int NB_SC  = (N + 1023) / 1024;
  const int NB_W4  = (N + 3) / 4;

  // ---- CSR build (dst-sorted src list), shared by both layers
  hipMemsetAsync(deg, 0, (size_t)N * 4, stream);
  hist_k<<<NB_E, 256, 0, stream>>>(dst, deg, E);
  scan_block_k<<<NB_SC, 1024, 0, stream>>>(deg, row_ptr, bsum, N);
  scan_sums_k<<<1, 64, 0, stream>>>(bsum, NB_SC);
  scan_add_k<<<NB_N, 256, 0, stream>>>(row_ptr, bsum, N);
  pos_init_k<<<NB_N, 256, 0, stream>>>(pos, row_ptr, N);
  scatter_k<<<NB_E, 256, 0, stream>>>(src, dst, pos, esrc, E);

  // ---- layer 1
  {
    dim3 g((N + 127) / 128, HD1 / 128);
    gemm_f32_k<128, 8><<<g, 256, 0, stream>>>(feats, W1, h1, N, HD1, IN);
  }
  elr1_k<<<NB_W4, 256, 0, stream>>>(h1, al1, ar1, el1, er1, N);
  agg1_k<<<NB_W4, 256, 0, stream>>>(h1, el1, er1, row_ptr, esrc, b1, x2, N);

  // ---- layer 2
  {
    dim3 g((N + 127) / 128, D2 / 64);
    gemm_f32_k<64, 4><<<g, 256, 0, stream>>>(x2, W2, h2, N, D2, HD1);
  }
  elr2_k<<<NB_W4, 256, 0, stream>>>(h2, al2, ar2, el2, er2, N);
  agg2_k<<<NB_W4, 256, 0, stream>>>(h2, el2, er2, row_ptr, esrc, b2, outp, N);
}

// Round 3
// 754.627 us; speedup vs baseline: 1.0357x; 1.0357x over previous
//
#include <hip/hip_runtime.h>
#include <hip/hip_bf16.h>
#include <math.h>

// ---------------------------------------------------------------------------
// GAT 2-layer forward. N=50000 nodes, E=800000 edges, 256 in-feats,
// layer1: 8 heads x 64, layer2: 1 head x 64. All fp32.
// ---------------------------------------------------------------------------

#define NEG_SLOPE 0.2f

__device__ __forceinline__ float lrelu(float x) { return x >= 0.f ? x : NEG_SLOPE * x; }

__device__ __forceinline__ float wred_max(float v) {
  #pragma unroll
  for (int off = 32; off; off >>= 1) v = fmaxf(v, __shfl_xor(v, off));
  return v;
}
__device__ __forceinline__ float wred_sum(float v) {
  #pragma unroll
  for (int off = 32; off; off >>= 1) v += __shfl_xor(v, off);
  return v;
}

// ---------------------------- CSR build ------------------------------------

__global__ __launch_bounds__(256) void hist_k(const int* __restrict__ dst, int* __restrict__ deg, int E) {
  int e = blockIdx.x * 256 + threadIdx.x;
  if (e < E) atomicAdd(&deg[dst[e]], 1);
}

__global__ __launch_bounds__(1024) void scan_block_k(const int* __restrict__ deg,
                                                     int* __restrict__ row_ptr,
                                                     int* __restrict__ bsum, int n) {
  __shared__ int sm[1024];
  int i = blockIdx.x * 1024 + threadIdx.x;
  int v = (i < n) ? deg[i] : 0;
  sm[threadIdx.x] = v;
  __syncthreads();
  for (int off = 1; off < 1024; off <<= 1) {
    int t = (threadIdx.x >= off) ? sm[threadIdx.x - off] : 0;
    __syncthreads();
    sm[threadIdx.x] += t;
    __syncthreads();
  }
  if (i < n) row_ptr[1 + i] = sm[threadIdx.x];
  if (threadIdx.x == 1023) bsum[blockIdx.x] = sm[1023];
}

__global__ void scan_sums_k(int* bsum, int nb) {
  if (threadIdx.x == 0 && blockIdx.x == 0) {
    int run = 0;
    for (int i = 0; i < nb; ++i) { int t = bsum[i]; bsum[i] = run; run += t; }
  }
}

__global__ __launch_bounds__(256) void scan_add_k(int* __restrict__ row_ptr, const int* __restrict__ bsum, int n) {
  int i = blockIdx.x * 256 + threadIdx.x;
  if (i < n) row_ptr[1 + i] += bsum[i / 1024];
  if (i == 0) row_ptr[0] = 0;
}

__global__ __launch_bounds__(256) void pos_init_k(int* __restrict__ pos, const int* __restrict__ row_ptr, int n) {
  int i = blockIdx.x * 256 + threadIdx.x;
  if (i < n) pos[i] = row_ptr[i];
}

__global__ __launch_bounds__(256) void scatter_k(const int* __restrict__ src, const int* __restrict__ dst,
                                                 int* __restrict__ pos, int* __restrict__ esrc, int E) {
  int e = blockIdx.x * 256 + threadIdx.x;
  if (e < E) {
    int slot = atomicAdd(&pos[dst[e]], 1);
    esrc[slot] = src[e];
  }
}

// ---------------------------- fp32 GEMM ------------------------------------

template <int BN, int TN>
__global__ __launch_bounds__(256) void gemm_f32_k(const float* __restrict__ A,
                                                  const float* __restrict__ B,
                                                  float* __restrict__ C,
                                                  int M, int N, int K) {
  constexpr int BM = 128, BK = 16, TM = 8;
  __shared__ float As[BK][BM + 4];
  __shared__ float Bs[BK][BN];
  const int tid = threadIdx.x;
  const int tx = tid & 15;
  const int ty = tid >> 4;
  const int row0 = blockIdx.x * BM;
  const int col0 = blockIdx.y * BN;

  float acc[TM][TN];
  #pragma unroll
  for (int i = 0; i < TM; ++i)
    #pragma unroll
    for (int j = 0; j < TN; ++j) acc[i][j] = 0.f;

  for (int k0 = 0; k0 < K; k0 += BK) {
    #pragma unroll
    for (int it = 0; it < (BM * BK / 4) / 256; ++it) {
      int f4 = tid + it * 256;
      int row = f4 >> 2;
      int c4 = f4 & 3;
      int grow = row0 + row;
      float4 v = make_float4(0.f, 0.f, 0.f, 0.f);
      if (grow < M) v = *(const float4*)(A + (size_t)grow * K + k0 + c4 * 4);
      As[c4 * 4 + 0][row] = v.x;
      As[c4 * 4 + 1][row] = v.y;
      As[c4 * 4 + 2][row] = v.z;
      As[c4 * 4 + 3][row] = v.w;
    }
    #pragma unroll
    for (int it = 0; it < (BK * BN / 4) / 256; ++it) {
      int f4 = tid + it * 256;
      int kk = f4 / (BN / 4);
      int n4 = f4 % (BN / 4);
      *(float4*)&Bs[kk][n4 * 4] = *(const float4*)(B + (size_t)(k0 + kk) * N + col0 + n4 * 4);
    }
    __syncthreads();
    #pragma unroll
    for (int kk = 0; kk < BK; ++kk) {
      float a[TM], b[TN];
      float4 a0 = *(const float4*)&As[kk][ty * TM];
      float4 a1 = *(const float4*)&As[kk][ty * TM + 4];
      a[0] = a0.x; a[1] = a0.y; a[2] = a0.z; a[3] = a0.w;
      a[4] = a1.x; a[5] = a1.y; a[6] = a1.z; a[7] = a1.w;
      #pragma unroll
      for (int j = 0; j < TN; j += 4) {
        float4 bv = *(const float4*)&Bs[kk][tx * TN + j];
        b[j] = bv.x; b[j + 1] = bv.y; b[j + 2] = bv.z; b[j + 3] = bv.w;
      }
      #pragma unroll
      for (int i = 0; i < TM; ++i)
        #pragma unroll
        for (int j = 0; j < TN; ++j) acc[i][j] = fmaf(a[i], b[j], acc[i][j]);
    }
    __syncthreads();
  }
  #pragma unroll
  for (int i = 0; i < TM; ++i) {
    int grow = row0 + ty * TM + i;
    if (grow < M) {
      #pragma unroll
      for (int j = 0; j < TN; j += 4) {
        float4 v = make_float4(acc[i][j], acc[i][j + 1], acc[i][j + 2], acc[i][j + 3]);
        *(float4*)(C + (size_t)grow * N + col0 + tx * TN + j) = v;
      }
    }
  }
}

// ------------------------- attention dot products --------------------------

__global__ __launch_bounds__(256) void elr1_k(const float* __restrict__ h1,
                                              const float* __restrict__ al,
                                              const float* __restrict__ ar,
                                              float* __restrict__ el, float* __restrict__ er, int N) {
  int wave = blockIdx.x * 4 + (threadIdx.x >> 6);
  int lane = threadIdx.x & 63;
  if (wave >= N) return;
  float alv[8], arv[8];
  #pragma unroll
  for (int h = 0; h < 8; ++h) { alv[h] = al[h * 64 + lane]; arv[h] = ar[h * 64 + lane]; }
  const float* hr = h1 + (size_t)wave * 512 + lane;
  float se[8], sr[8];
  #pragma unroll
  for (int h = 0; h < 8; ++h) {
    float v = hr[h * 64];
    se[h] = v * alv[h];
    sr[h] = v * arv[h];
  }
  #pragma unroll
  for (int off = 32; off; off >>= 1) {
    #pragma unroll
    for (int h = 0; h < 8; ++h) {
      se[h] += __shfl_xor(se[h], off);
      sr[h] += __shfl_xor(sr[h], off);
    }
  }
  if (lane == 0) {
    #pragma unroll
    for (int h = 0; h < 8; ++h) {
      el[(size_t)wave * 8 + h] = se[h];
      er[(size_t)wave * 8 + h] = sr[h];
    }
  }
}

__global__ __launch_bounds__(256) void elr2_k(const float* __restrict__ h2,
                                              const float* __restrict__ al,
                                              const float* __restrict__ ar,
                                              float* __restrict__ el, float* __restrict__ er, int N) {
  int wave = blockIdx.x * 4 + (threadIdx.x >> 6);
  int lane = threadIdx.x & 63;
  if (wave >= N) return;
  float v = h2[(size_t)wave * 64 + lane];
  float sl = v * al[lane];
  float sr = v * ar[lane];
  sl = wred_sum(sl);
  sr = wred_sum(sr);
  if (lane == 0) { el[wave] = sl; er[wave] = sr; }
}

// ------------------------- aggregation (edge softmax + SpMM) ----------------

// layer1: 2 waves per node; wave handles 4 heads (half*256 .. +256 dims).
// Lane l owns float4 at dims half*256 + l*4; its head = half*4 + (l>>4).
// Stats: lane-per-edge batches of 64, p/src stashed in LDS; gather: 4 edges
// per unrolled step, one float4 load per lane per edge (1KB/wave contiguous).
__global__ __launch_bounds__(256) void agg1_k(const float* __restrict__ h1,
                                              const float* __restrict__ el,
                                              const float* __restrict__ er,
                                              const int* __restrict__ row_ptr,
                                              const int* __restrict__ esrc,
                                              const float* __restrict__ b1,
                                              float* __restrict__ x2, int N) {
  __shared__ float p_lds[4][64][4];
  __shared__ int   s_lds[4][64];
  const int widx = threadIdx.x >> 6;
  const int lane = threadIdx.x & 63;
  const int gw = blockIdx.x * 4 + widx;
  const int n = gw >> 1;
  const int half = gw & 1;
  if (n >= N) return;
  const int start = row_ptr[n], end = row_ptr[n + 1];
  const int hg = lane >> 4;   // which of my wave's 4 heads this lane's dims belong to

  float4 er4 = *(const float4*)(er + (size_t)n * 8 + half * 4);
  float erh[4] = {er4.x, er4.y, er4.z, er4.w};

  float4 acc = make_float4(0.f, 0.f, 0.f, 0.f);
  float m[4], denom[4];
  #pragma unroll
  for (int h = 0; h < 4; ++h) { m[h] = -INFINITY; denom[h] = 0.f; }

  for (int base = start; base < end; base += 64) {
    int j = base + lane;
    bool valid = j < end;
    int s = valid ? esrc[j] : 0;

    float4 e4 = *(const float4*)(el + (size_t)s * 8 + half * 4);
    float sc[4];
    sc[0] = lrelu(e4.x + erh[0]); sc[1] = lrelu(e4.y + erh[1]);
    sc[2] = lrelu(e4.z + erh[2]); sc[3] = lrelu(e4.w + erh[3]);
    if (!valid) { sc[0] = sc[1] = sc[2] = sc[3] = -INFINITY; }

    float p[4], fs[4];
    #pragma unroll
    for (int h = 0; h < 4; ++h) {
      float bm = wred_max(sc[h]);
      float nm = fmaxf(m[h], bm);
      fs[h] = expf(m[h] - nm);      // 0 when m was -inf
      m[h] = nm;
      p[h] = valid ? expf(sc[h] - nm) : 0.f;
      denom[h] = denom[h] * fs[h] + wred_sum(p[h]);
    }
    float fmine = hg == 0 ? fs[0] : hg == 1 ? fs[1] : hg == 2 ? fs[2] : fs[3];
    acc.x *= fmine; acc.y *= fmine; acc.z *= fmine; acc.w *= fmine;

    *(float4*)&p_lds[widx][lane][0] = make_float4(p[0], p[1], p[2], p[3]);
    s_lds[widx][lane] = s;

    const int cnt = min(64, end - base);
    const float* __restrict__ hbase = h1 + (size_t)half * 256 + lane * 4;
    int jj = 0;
    for (; jj + 4 <= cnt; jj += 4) {
      int   ss[4];
      float a[4];
      float4 hv[4];
      #pragma unroll
      for (int u = 0; u < 4; ++u) ss[u] = s_lds[widx][jj + u];
      #pragma unroll
      for (int u = 0; u < 4; ++u) a[u] = p_lds[widx][jj + u][hg];
      #pragma unroll
      for (int u = 0; u < 4; ++u) hv[u] = *(const float4*)(hbase + (size_t)ss[u] * 512);
      #pragma unroll
      for (int u = 0; u < 4; ++u) {
        acc.x = fmaf(a[u], hv[u].x, acc.x);
        acc.y = fmaf(a[u], hv[u].y, acc.y);
        acc.z = fmaf(a[u], hv[u].z, acc.z);
        acc.w = fmaf(a[u], hv[u].w, acc.w);
      }
    }
    for (; jj < cnt; ++jj) {
      int ss = s_lds[widx][jj];
      float a = p_lds[widx][jj][hg];
      float4 hv = *(const float4*)(hbase + (size_t)ss * 512);
      acc.x = fmaf(a, hv.x, acc.x);
      acc.y = fmaf(a, hv.y, acc.y);
      acc.z = fmaf(a, hv.z, acc.z);
      acc.w = fmaf(a, hv.w, acc.w);
    }
  }

  const int deg = end - start;
  float dh = hg == 0 ? denom[0] : hg == 1 ? denom[1] : hg == 2 ? denom[2] : denom[3];
  float inv = deg ? 1.f / dh : 0.f;
  float4 bv = *(const float4*)(b1 + half * 256 + lane * 4);
  float4 o;
  o.x = fmaxf(acc.x * inv + bv.x, 0.f);
  o.y = fmaxf(acc.y * inv + bv.y, 0.f);
  o.z = fmaxf(acc.z * inv + bv.z, 0.f);
  o.w = fmaxf(acc.w * inv + bv.w, 0.f);
  *(float4*)(x2 + (size_t)n * 512 + half * 256 + lane * 4) = o;
}

// layer2: 1 head x 64 dims. Wave per node. Stats lane-per-edge (64/batch),
// gather 4 edges in parallel via 16-lane groups, float4 per lane.
__global__ __launch_bounds__(256) void agg2_k(const float* __restrict__ h2,
                                              const float* __restrict__ el,
                                              const float* __restrict__ er,
                                              const int* __restrict__ row_ptr,
                                              const int* __restrict__ esrc,
                                              const float* __restrict__ b2,
                                              float* __restrict__ out, int N) {
  __shared__ float p_lds[4][64];
  __shared__ int   s_lds[4][64];
  const int widx = threadIdx.x >> 6;
  const int lane = threadIdx.x & 63;
  const int n = blockIdx.x * 4 + widx;
  if (n >= N) return;
  const int start = row_ptr[n], end = row_ptr[n + 1];
  const int eg = lane >> 4;   // edge subgroup
  const int dg = lane & 15;   // dim group (dims dg*4..dg*4+3)
  const float ern = er[n];

  float4 acc = make_float4(0.f, 0.f, 0.f, 0.f);
  float m = -INFINITY, denom = 0.f;

  for (int base = start; base < end; base += 64) {
    int j = base + lane;
    bool valid = j < end;
    int s = valid ? esrc[j] : 0;
    float sc = valid ? lrelu(el[s] + ern) : -INFINITY;
    float bm = wred_max(sc);
    float nm = fmaxf(m, bm);
    float f = expf(m - nm);
    m = nm;
    float p = valid ? expf(sc - nm) : 0.f;
    denom = denom * f + wred_sum(p);
    acc.x *= f; acc.y *= f; acc.z *= f; acc.w *= f;

    p_lds[widx][lane] = p;
    s_lds[widx][lane] = s;

    const int cnt = min(64, end - base);
    for (int jj = 0; jj < cnt; jj += 4) {
      int myj = jj + eg;
      bool v2 = myj < cnt;
      int ss = s_lds[widx][v2 ? myj : 0];
      float a = v2 ? p_lds[widx][myj] : 0.f;
      float4 hv = *(const float4*)(h2 + (size_t)ss * 64 + dg * 4);
      acc.x = fmaf(a, hv.x, acc.x);
      acc.y = fmaf(a, hv.y, acc.y);
      acc.z = fmaf(a, hv.z, acc.z);
      acc.w = fmaf(a, hv.w, acc.w);
    }
  }

  // reduce the 4 edge-subgroup partial accs (lanes with same dg share dims)
  #pragma unroll
  for (int off = 16; off <= 32; off <<= 1) {
    acc.x += __shfl_xor(acc.x, off);
    acc.y += __shfl_xor(acc.y, off);
    acc.z += __shfl_xor(acc.z, off);
    acc.w += __shfl_xor(acc.w, off);
  }

  if (eg == 0) {
    const int deg = end - start;
    float inv = deg ? 1.f / denom : 0.f;
    float4 bv = *(const float4*)(b2 + dg * 4);
    float4 o;
    o.x = acc.x * inv + bv.x;
    o.y = acc.y * inv + bv.y;
    o.z = acc.z * inv + bv.z;
    o.w = acc.w * inv + bv.w;
    *(float4*)(out + (size_t)n * 64 + dg * 4) = o;
  }
}

// ---------------------------------------------------------------------------

extern "C" void kernel_launch(void* const* d_in, const int* in_sizes, int n_in,
                              void* d_out, int out_size, void* d_ws, size_t ws_size,
                              hipStream_t stream) {
  const float* feats = (const float*)d_in[0];
  const float* W1    = (const float*)d_in[1];
  const float* al1   = (const float*)d_in[2];
  const float* ar1   = (const float*)d_in[3];
  const float* b1    = (const float*)d_in[4];
  const float* W2    = (const float*)d_in[5];
  const float* al2   = (const float*)d_in[6];
  const float* ar2   = (const float*)d_in[7];
  const float* b2    = (const float*)d_in[8];
  const int*   src   = (const int*)d_in[9];
  const int*   dst   = (const int*)d_in[10];

  const int N = in_sizes[0] / 256;   // 50000
  const int E = in_sizes[9];         // 800000
  const int IN = 256, HD1 = 512, D2 = 64;

  char* w = (char*)d_ws;
  size_t off = 0;
  auto alloc = [&](size_t bytes) -> void* {
    void* p = w + off;
    off = (off + bytes + 255) & ~(size_t)255;
    return p;
  };
  float* h1      = (float*)alloc((size_t)N * HD1 * 4);
  float* x2      = (float*)alloc((size_t)N * HD1 * 4);
  float* h2      = (float*)alloc((size_t)N * D2 * 4);
  float* el1     = (float*)alloc((size_t)N * 8 * 4);
  float* er1     = (float*)alloc((size_t)N * 8 * 4);
  float* el2     = (float*)alloc((size_t)N * 4);
  float* er2     = (float*)alloc((size_t)N * 4);
  int*   deg     = (int*)alloc((size_t)N * 4);
  int*   row_ptr = (int*)alloc((size_t)(N + 1) * 4);
  int*   pos     = (int*)alloc((size_t)N * 4);
  int*   bsum    = (int*)alloc(64 * 4);
  int*   esrc    = (int*)alloc((size_t)E * 4);

  float* outp = (float*)d_out;

  const int NB_E   = (E + 255) / 256;
  const int NB_N   = (N + 255) / 256;
  const int NB_SC  = (N + 1023) / 1024;
  const int NB_W4  = (N + 3) / 4;
  const int NB_AG1 = (2 * N + 3) / 4;

  // ---- CSR build (dst-sorted src list), shared by both layers
  hipMemsetAsync(deg, 0, (size_t)N * 4, stream);
  hist_k<<<NB_E, 256, 0, stream>>>(dst, deg, E);
  scan_block_k<<<NB_SC, 1024, 0, stream>>>(deg, row_ptr, bsum, N);
  scan_sums_k<<<1, 64, 0, stream>>>(bsum, NB_SC);
  scan_add_k<<<NB_N, 256, 0, stream>>>(row_ptr, bsum, N);
  pos_init_k<<<NB_N, 256, 0, stream>>>(pos, row_ptr, N);
  scatter_k<<<NB_E, 256, 0, stream>>>(src, dst, pos, esrc, E);

  // ---- layer 1
  {
    dim3 g((N + 127) / 128, HD1 / 128);
    gemm_f32_k<128, 8><<<g, 256, 0, stream>>>(feats, W1, h1, N, HD1, IN);
  }
  elr1_k<<<NB_W4, 256, 0, stream>>>(h1, al1, ar1, el1, er1, N);
  agg1_k<<<NB_AG1, 256, 0, stream>>>(h1, el1, er1, row_ptr, esrc, b1, x2, N);

  // ---- layer 2
  {
    dim3 g((N + 127) / 128, D2 / 64);
    gemm_f32_k<64, 4><<<g, 256, 0, stream>>>(x2, W2, h2, N, D2, HD1);
  }
  elr2_k<<<NB_W4, 256, 0, stream>>>(h2, al2, ar2, el2, er2, N);
  agg2_k<<<NB_W4, 256, 0, stream>>>(h2, el2, er2, row_ptr, esrc, b2, outp, N);
}

// Round 7
// 647.120 us; speedup vs baseline: 1.2078x; 1.1661x over previous
//
#include <hip/hip_runtime.h>
#include <hip/hip_bf16.h>
#include <hip/hip_fp16.h>
#include <math.h>

// ---------------------------------------------------------------------------
// GAT 2-layer forward. N=50000 nodes, E=800000 edges, 256 in-feats,
// layer1: 8 heads x 64, layer2: 1 head x 64.
// h1 (layer-1 projected features) is stored in fp16: the agg1 edge-gather is
// bandwidth-bound at the L2-miss level (8 XCDs x 102MB fp32 = measured 819MB
// FETCH at a ~3.75 TB/s wall), so halving bytes is the only lever. All other
// arithmetic stays fp32.
// ---------------------------------------------------------------------------

#define NEG_SLOPE 0.2f

__device__ __forceinline__ float lrelu(float x) { return x >= 0.f ? x : NEG_SLOPE * x; }

__device__ __forceinline__ float wred_max(float v) {
  #pragma unroll
  for (int off = 32; off; off >>= 1) v = fmaxf(v, __shfl_xor(v, off));
  return v;
}
__device__ __forceinline__ float wred_sum(float v) {
  #pragma unroll
  for (int off = 32; off; off >>= 1) v += __shfl_xor(v, off);
  return v;
}

// ---------------------------- CSR build ------------------------------------

__global__ __launch_bounds__(256) void hist_k(const int* __restrict__ dst, int* __restrict__ deg, int E) {
  int e = blockIdx.x * 256 + threadIdx.x;
  if (e < E) atomicAdd(&deg[dst[e]], 1);
}

__global__ __launch_bounds__(1024) void scan_block_k(const int* __restrict__ deg,
                                                     int* __restrict__ row_ptr,
                                                     int* __restrict__ bsum, int n) {
  __shared__ int sm[1024];
  int i = blockIdx.x * 1024 + threadIdx.x;
  int v = (i < n) ? deg[i] : 0;
  sm[threadIdx.x] = v;
  __syncthreads();
  for (int off = 1; off < 1024; off <<= 1) {
    int t = (threadIdx.x >= off) ? sm[threadIdx.x - off] : 0;
    __syncthreads();
    sm[threadIdx.x] += t;
    __syncthreads();
  }
  if (i < n) row_ptr[1 + i] = sm[threadIdx.x];
  if (threadIdx.x == 1023) bsum[blockIdx.x] = sm[1023];
}

__global__ void scan_sums_k(int* bsum, int nb) {
  if (threadIdx.x == 0 && blockIdx.x == 0) {
    int run = 0;
    for (int i = 0; i < nb; ++i) { int t = bsum[i]; bsum[i] = run; run += t; }
  }
}

__global__ __launch_bounds__(256) void scan_add_k(int* __restrict__ row_ptr, const int* __restrict__ bsum, int n) {
  int i = blockIdx.x * 256 + threadIdx.x;
  if (i < n) row_ptr[1 + i] += bsum[i / 1024];
  if (i == 0) row_ptr[0] = 0;
}

__global__ __launch_bounds__(256) void pos_init_k(int* __restrict__ pos, const int* __restrict__ row_ptr, int n) {
  int i = blockIdx.x * 256 + threadIdx.x;
  if (i < n) pos[i] = row_ptr[i];
}

__global__ __launch_bounds__(256) void scatter_k(const int* __restrict__ src, const int* __restrict__ dst,
                                                 int* __restrict__ pos, int* __restrict__ esrc, int E) {
  int e = blockIdx.x * 256 + threadIdx.x;
  if (e < E) {
    int slot = atomicAdd(&pos[dst[e]], 1);
    esrc[slot] = src[e];
  }
}

// ---------------------------- fp32 GEMM ------------------------------------
// HOUT: write C as fp16 (round-to-nearest) instead of fp32.

template <int BN, int TN, bool HOUT>
__global__ __launch_bounds__(256) void gemm_f32_k(const float* __restrict__ A,
                                                  const float* __restrict__ B,
                                                  void* __restrict__ Cv,
                                                  int M, int N, int K) {
  constexpr int BM = 128, BK = 16, TM = 8;
  __shared__ float As[BK][BM + 4];
  __shared__ float Bs[BK][BN];
  const int tid = threadIdx.x;
  const int tx = tid & 15;
  const int ty = tid >> 4;
  const int row0 = blockIdx.x * BM;
  const int col0 = blockIdx.y * BN;

  float acc[TM][TN];
  #pragma unroll
  for (int i = 0; i < TM; ++i)
    #pragma unroll
    for (int j = 0; j < TN; ++j) acc[i][j] = 0.f;

  for (int k0 = 0; k0 < K; k0 += BK) {
    #pragma unroll
    for (int it = 0; it < (BM * BK / 4) / 256; ++it) {
      int f4 = tid + it * 256;
      int row = f4 >> 2;
      int c4 = f4 & 3;
      int grow = row0 + row;
      float4 v = make_float4(0.f, 0.f, 0.f, 0.f);
      if (grow < M) v = *(const float4*)(A + (size_t)grow * K + k0 + c4 * 4);
      As[c4 * 4 + 0][row] = v.x;
      As[c4 * 4 + 1][row] = v.y;
      As[c4 * 4 + 2][row] = v.z;
      As[c4 * 4 + 3][row] = v.w;
    }
    #pragma unroll
    for (int it = 0; it < (BK * BN / 4) / 256; ++it) {
      int f4 = tid + it * 256;
      int kk = f4 / (BN / 4);
      int n4 = f4 % (BN / 4);
      *(float4*)&Bs[kk][n4 * 4] = *(const float4*)(B + (size_t)(k0 + kk) * N + col0 + n4 * 4);
    }
    __syncthreads();
    #pragma unroll
    for (int kk = 0; kk < BK; ++kk) {
      float a[TM], b[TN];
      float4 a0 = *(const float4*)&As[kk][ty * TM];
      float4 a1 = *(const float4*)&As[kk][ty * TM + 4];
      a[0] = a0.x; a[1] = a0.y; a[2] = a0.z; a[3] = a0.w;
      a[4] = a1.x; a[5] = a1.y; a[6] = a1.z; a[7] = a1.w;
      #pragma unroll
      for (int j = 0; j < TN; j += 4) {
        float4 bv = *(const float4*)&Bs[kk][tx * TN + j];
        b[j] = bv.x; b[j + 1] = bv.y; b[j + 2] = bv.z; b[j + 3] = bv.w;
      }
      #pragma unroll
      for (int i = 0; i < TM; ++i)
        #pragma unroll
        for (int j = 0; j < TN; ++j) acc[i][j] = fmaf(a[i], b[j], acc[i][j]);
    }
    __syncthreads();
  }
  #pragma unroll
  for (int i = 0; i < TM; ++i) {
    int grow = row0 + ty * TM + i;
    if (grow < M) {
      #pragma unroll
      for (int j = 0; j < TN; j += 4) {
        if constexpr (HOUT) {
          __half2 p0 = __floats2half2_rn(acc[i][j], acc[i][j + 1]);
          __half2 p1 = __floats2half2_rn(acc[i][j + 2], acc[i][j + 3]);
          uint2 u;
          u.x = *(unsigned int*)&p0;
          u.y = *(unsigned int*)&p1;
          *(uint2*)((__half*)Cv + (size_t)grow * N + col0 + tx * TN + j) = u;
        } else {
          float4 v = make_float4(acc[i][j], acc[i][j + 1], acc[i][j + 2], acc[i][j + 3]);
          *(float4*)((float*)Cv + (size_t)grow * N + col0 + tx * TN + j) = v;
        }
      }
    }
  }
}

// ------------------------- attention dot products --------------------------

// layer1: el[n,h] = sum_d h1[n,h*64+d]*attn_l[h,d]; one wave per node (h1 fp16)
__global__ __launch_bounds__(256) void elr1_k(const __half* __restrict__ h1,
                                              const float* __restrict__ al,
                                              const float* __restrict__ ar,
                                              float* __restrict__ el, float* __restrict__ er, int N) {
  int wave = blockIdx.x * 4 + (threadIdx.x >> 6);
  int lane = threadIdx.x & 63;
  if (wave >= N) return;
  float alv[8], arv[8];
  #pragma unroll
  for (int h = 0; h < 8; ++h) { alv[h] = al[h * 64 + lane]; arv[h] = ar[h * 64 + lane]; }
  const __half* hr = h1 + (size_t)wave * 512 + lane;
  float se[8], sr[8];
  #pragma unroll
  for (int h = 0; h < 8; ++h) {
    float v = __half2float(hr[h * 64]);
    se[h] = v * alv[h];
    sr[h] = v * arv[h];
  }
  #pragma unroll
  for (int off = 32; off; off >>= 1) {
    #pragma unroll
    for (int h = 0; h < 8; ++h) {
      se[h] += __shfl_xor(se[h], off);
      sr[h] += __shfl_xor(sr[h], off);
    }
  }
  if (lane == 0) {
    #pragma unroll
    for (int h = 0; h < 8; ++h) {
      el[(size_t)wave * 8 + h] = se[h];
      er[(size_t)wave * 8 + h] = sr[h];
    }
  }
}

__global__ __launch_bounds__(256) void elr2_k(const float* __restrict__ h2,
                                              const float* __restrict__ al,
                                              const float* __restrict__ ar,
                                              float* __restrict__ el, float* __restrict__ er, int N) {
  int wave = blockIdx.x * 4 + (threadIdx.x >> 6);
  int lane = threadIdx.x & 63;
  if (wave >= N) return;
  float v = h2[(size_t)wave * 64 + lane];
  float sl = v * al[lane];
  float sr = v * ar[lane];
  sl = wred_sum(sl);
  sr = wred_sum(sr);
  if (lane == 0) { el[wave] = sl; er[wave] = sr; }
}

// ------------------------- aggregation (edge softmax + SpMM) ----------------

// layer1: 2 waves per node; wave handles 4 heads (half*256 .. +256 dims).
// Lane l owns 4 dims at half*256 + l*4 (fp16 gather: 8B/lane/edge).
__global__ __launch_bounds__(256) void agg1_k(const __half* __restrict__ h1,
                                              const float* __restrict__ el,
                                              const float* __restrict__ er,
                                              const int* __restrict__ row_ptr,
                                              const int* __restrict__ esrc,
                                              const float* __restrict__ b1,
                                              float* __restrict__ x2, int N) {
  __shared__ float p_lds[4][64][4];
  __shared__ int   s_lds[4][64];
  const int widx = threadIdx.x >> 6;
  const int lane = threadIdx.x & 63;
  const int gw = blockIdx.x * 4 + widx;
  const int n = gw >> 1;
  const int half = gw & 1;
  if (n >= N) return;
  const int start = row_ptr[n], end = row_ptr[n + 1];
  const int hg = lane >> 4;   // which of my wave's 4 heads this lane's dims belong to

  float4 er4 = *(const float4*)(er + (size_t)n * 8 + half * 4);
  float erh[4] = {er4.x, er4.y, er4.z, er4.w};

  float4 acc = make_float4(0.f, 0.f, 0.f, 0.f);
  float m[4], denom[4];
  #pragma unroll
  for (int h = 0; h < 4; ++h) { m[h] = -INFINITY; denom[h] = 0.f; }

  for (int base = start; base < end; base += 64) {
    int j = base + lane;
    bool valid = j < end;
    int s = valid ? esrc[j] : 0;

    float4 e4 = *(const float4*)(el + (size_t)s * 8 + half * 4);
    float sc[4];
    sc[0] = lrelu(e4.x + erh[0]); sc[1] = lrelu(e4.y + erh[1]);
    sc[2] = lrelu(e4.z + erh[2]); sc[3] = lrelu(e4.w + erh[3]);
    if (!valid) { sc[0] = sc[1] = sc[2] = sc[3] = -INFINITY; }

    float p[4], fs[4];
    #pragma unroll
    for (int h = 0; h < 4; ++h) {
      float bm = wred_max(sc[h]);
      float nm = fmaxf(m[h], bm);
      fs[h] = expf(m[h] - nm);      // 0 when m was -inf
      m[h] = nm;
      p[h] = valid ? expf(sc[h] - nm) : 0.f;
      denom[h] = denom[h] * fs[h] + wred_sum(p[h]);
    }
    float fmine = hg == 0 ? fs[0] : hg == 1 ? fs[1] : hg == 2 ? fs[2] : fs[3];
    acc.x *= fmine; acc.y *= fmine; acc.z *= fmine; acc.w *= fmine;

    *(float4*)&p_lds[widx][lane][0] = make_float4(p[0], p[1], p[2], p[3]);
    s_lds[widx][lane] = s;

    const int cnt = min(64, end - base);
    const __half* __restrict__ hbase = h1 + (size_t)half * 256 + lane * 4;
    int jj = 0;
    for (; jj + 4 <= cnt; jj += 4) {
      int   ss[4];
      float a[4];
      uint2 hv[4];
      #pragma unroll
      for (int u = 0; u < 4; ++u) ss[u] = s_lds[widx][jj + u];
      #pragma unroll
      for (int u = 0; u < 4; ++u) a[u] = p_lds[widx][jj + u][hg];
      #pragma unroll
      for (int u = 0; u < 4; ++u) hv[u] = *(const uint2*)(hbase + (size_t)ss[u] * 512);
      #pragma unroll
      for (int u = 0; u < 4; ++u) {
        float2 f01 = __half22float2(*(__half2*)&hv[u].x);
        float2 f23 = __half22float2(*(__half2*)&hv[u].y);
        acc.x = fmaf(a[u], f01.x, acc.x);
        acc.y = fmaf(a[u], f01.y, acc.y);
        acc.z = fmaf(a[u], f23.x, acc.z);
        acc.w = fmaf(a[u], f23.y, acc.w);
      }
    }
    for (; jj < cnt; ++jj) {
      int ss = s_lds[widx][jj];
      float a = p_lds[widx][jj][hg];
      uint2 hv = *(const uint2*)(hbase + (size_t)ss * 512);
      float2 f01 = __half22float2(*(__half2*)&hv.x);
      float2 f23 = __half22float2(*(__half2*)&hv.y);
      acc.x = fmaf(a, f01.x, acc.x);
      acc.y = fmaf(a, f01.y, acc.y);
      acc.z = fmaf(a, f23.x, acc.z);
      acc.w = fmaf(a, f23.y, acc.w);
    }
  }

  const int deg = end - start;
  float dh = hg == 0 ? denom[0] : hg == 1 ? denom[1] : hg == 2 ? denom[2] : denom[3];
  float inv = deg ? 1.f / dh : 0.f;
  float4 bv = *(const float4*)(b1 + half * 256 + lane * 4);
  float4 o;
  o.x = fmaxf(acc.x * inv + bv.x, 0.f);
  o.y = fmaxf(acc.y * inv + bv.y, 0.f);
  o.z = fmaxf(acc.z * inv + bv.z, 0.f);
  o.w = fmaxf(acc.w * inv + bv.w, 0.f);
  *(float4*)(x2 + (size_t)n * 512 + half * 256 + lane * 4) = o;
}

// layer2: 1 head x 64 dims. Wave per node. Stats lane-per-edge (64/batch),
// gather 4 edges in parallel via 16-lane groups, float4 per lane.
__global__ __launch_bounds__(256) void agg2_k(const float* __restrict__ h2,
                                              const float* __restrict__ el,
                                              const float* __restrict__ er,
                                              const int* __restrict__ row_ptr,
                                              const int* __restrict__ esrc,
                                              const float* __restrict__ b2,
                                              float* __restrict__ out, int N) {
  __shared__ float p_lds[4][64];
  __shared__ int   s_lds[4][64];
  const int widx = threadIdx.x >> 6;
  const int lane = threadIdx.x & 63;
  const int n = blockIdx.x * 4 + widx;
  if (n >= N) return;
  const int start = row_ptr[n], end = row_ptr[n + 1];
  const int eg = lane >> 4;   // edge subgroup
  const int dg = lane & 15;   // dim group (dims dg*4..dg*4+3)
  const float ern = er[n];

  float4 acc = make_float4(0.f, 0.f, 0.f, 0.f);
  float m = -INFINITY, denom = 0.f;

  for (int base = start; base < end; base += 64) {
    int j = base + lane;
    bool valid = j < end;
    int s = valid ? esrc[j] : 0;
    float sc = valid ? lrelu(el[s] + ern) : -INFINITY;
    float bm = wred_max(sc);
    float nm = fmaxf(m, bm);
    float f = expf(m - nm);
    m = nm;
    float p = valid ? expf(sc - nm) : 0.f;
    denom = denom * f + wred_sum(p);
    acc.x *= f; acc.y *= f; acc.z *= f; acc.w *= f;

    p_lds[widx][lane] = p;
    s_lds[widx][lane] = s;

    const int cnt = min(64, end - base);
    for (int jj = 0; jj < cnt; jj += 4) {
      int myj = jj + eg;
      bool v2 = myj < cnt;
      int ss = s_lds[widx][v2 ? myj : 0];
      float a = v2 ? p_lds[widx][myj] : 0.f;
      float4 hv = *(const float4*)(h2 + (size_t)ss * 64 + dg * 4);
      acc.x = fmaf(a, hv.x, acc.x);
      acc.y = fmaf(a, hv.y, acc.y);
      acc.z = fmaf(a, hv.z, acc.z);
      acc.w = fmaf(a, hv.w, acc.w);
    }
  }

  // reduce the 4 edge-subgroup partial accs (lanes with same dg share dims)
  #pragma unroll
  for (int off = 16; off <= 32; off <<= 1) {
    acc.x += __shfl_xor(acc.x, off);
    acc.y += __shfl_xor(acc.y, off);
    acc.z += __shfl_xor(acc.z, off);
    acc.w += __shfl_xor(acc.w, off);
  }

  if (eg == 0) {
    const int deg = end - start;
    float inv = deg ? 1.f / denom : 0.f;
    float4 bv = *(const float4*)(b2 + dg * 4);
    float4 o;
    o.x = acc.x * inv + bv.x;
    o.y = acc.y * inv + bv.y;
    o.z = acc.z * inv + bv.z;
    o.w = acc.w * inv + bv.w;
    *(float4*)(out + (size_t)n * 64 + dg * 4) = o;
  }
}

// ---------------------------------------------------------------------------

extern "C" void kernel_launch(void* const* d_in, const int* in_sizes, int n_in,
                              void* d_out, int out_size, void* d_ws, size_t ws_size,
                              hipStream_t stream) {
  const float* feats = (const float*)d_in[0];
  const float* W1    = (const float*)d_in[1];
  const float* al1   = (const float*)d_in[2];
  const float* ar1   = (const float*)d_in[3];
  const float* b1    = (const float*)d_in[4];
  const float* W2    = (const float*)d_in[5];
  const float* al2   = (const float*)d_in[6];
  const float* ar2   = (const float*)d_in[7];
  const float* b2    = (const float*)d_in[8];
  const int*   src   = (const int*)d_in[9];
  const int*   dst   = (const int*)d_in[10];

  const int N = in_sizes[0] / 256;   // 50000
  const int E = in_sizes[9];         // 800000
  const int IN = 256, HD1 = 512, D2 = 64;

  char* w = (char*)d_ws;
  size_t off = 0;
  auto alloc = [&](size_t bytes) -> void* {
    void* p = w + off;
    off = (off + bytes + 255) & ~(size_t)255;
    return p;
  };
  __half* h1h    = (__half*)alloc((size_t)N * HD1 * 2);
  float* x2      = (float*)alloc((size_t)N * HD1 * 4);
  float* h2      = (float*)alloc((size_t)N * D2 * 4);
  float* el1     = (float*)alloc((size_t)N * 8 * 4);
  float* er1     = (float*)alloc((size_t)N * 8 * 4);
  float* el2     = (float*)alloc((size_t)N * 4);
  float* er2     = (float*)alloc((size_t)N * 4);
  int*   deg     = (int*)alloc((size_t)N * 4);
  int*   row_ptr = (int*)alloc((size_t)(N + 1) * 4);
  int*   pos     = (int*)alloc((size_t)N * 4);
  int*   bsum    = (int*)alloc(64 * 4);
  int*   esrc    = (int*)alloc((size_t)E * 4);

  float* outp = (float*)d_out;

  const int NB_E   = (E + 255) / 256;
  const int NB_N   = (N + 255) / 256;
  const int NB_SC  = (N + 1023) / 1024;
  const int NB_W4  = (N + 3) / 4;
  const int NB_AG1 = (2 * N + 3) / 4;

  // ---- CSR build (dst-sorted src list), shared by both layers
  hipMemsetAsync(deg, 0, (size_t)N * 4, stream);
  hist_k<<<NB_E, 256, 0, stream>>>(dst, deg, E);
  scan_block_k<<<NB_SC, 1024, 0, stream>>>(deg, row_ptr, bsum, N);
  scan_sums_k<<<1, 64, 0, stream>>>(bsum, NB_SC);
  scan_add_k<<<NB_N, 256, 0, stream>>>(row_ptr, bsum, N);
  pos_init_k<<<NB_N, 256, 0, stream>>>(pos, row_ptr, N);
  scatter_k<<<NB_E, 256, 0, stream>>>(src, dst, pos, esrc, E);

  // ---- layer 1 (h1 stored fp16)
  {
    dim3 g((N + 127) / 128, HD1 / 128);
    gemm_f32_k<128, 8, true><<<g, 256, 0, stream>>>(feats, W1, h1h, N, HD1, IN);
  }
  elr1_k<<<NB_W4, 256, 0, stream>>>(h1h, al1, ar1, el1, er1, N);
  agg1_k<<<NB_AG1, 256, 0, stream>>>(h1h, el1, er1, row_ptr, esrc, b1, x2, N);

  // ---- layer 2
  {
    dim3 g((N + 127) / 128, D2 / 64);
    gemm_f32_k<64, 4, false><<<g, 256, 0, stream>>>(x2, W2, h2, N, D2, HD1);
  }
  elr2_k<<<NB_W4, 256, 0, stream>>>(h2, al2, ar2, el2, er2, N);
  agg2_k<<<NB_W4, 256, 0, stream>>>(h2, el2, er2, row_ptr, esrc, b2, outp, N);
}

// Round 8
// 581.606 us; speedup vs baseline: 1.3438x; 1.1126x over previous
//
#include <hip/hip_runtime.h>
#include <hip/hip_bf16.h>
#include <hip/hip_fp16.h>
#include <math.h>

// ---------------------------------------------------------------------------
// GAT 2-layer forward. N=50000 nodes, E=800000 edges, 256 in-feats,
// layer1: 8 heads x 64, layer2: 1 head x 64.
// h1 stored fp16 (agg1 gather is L2-miss-BW-bound: 8 XCDs replicate the h1
// table; fp32->fp16 halved FETCH 819->~410MB, -107us total, r7).
// GEMM1 now fp16-input MFMA (mfma_f32_16x16x32_f16, fp32 acc): the fp32
// vector GEMM was 178us at 47% of the 157TF vector ceiling with MfmaUtil=0.
// ---------------------------------------------------------------------------

#define NEG_SLOPE 0.2f

typedef _Float16 f16x8 __attribute__((ext_vector_type(8)));
typedef _Float16 f16x4 __attribute__((ext_vector_type(4)));
typedef float f32x4 __attribute__((ext_vector_type(4)));

__device__ __forceinline__ float lrelu(float x) { return x >= 0.f ? x : NEG_SLOPE * x; }

__device__ __forceinline__ float wred_max(float v) {
  #pragma unroll
  for (int off = 32; off; off >>= 1) v = fmaxf(v, __shfl_xor(v, off));
  return v;
}
__device__ __forceinline__ float wred_sum(float v) {
  #pragma unroll
  for (int off = 32; off; off >>= 1) v += __shfl_xor(v, off);
  return v;
}

// ---------------------------- CSR build ------------------------------------

__global__ __launch_bounds__(256) void hist_k(const int* __restrict__ dst, int* __restrict__ deg, int E) {
  int e = blockIdx.x * 256 + threadIdx.x;
  if (e < E) atomicAdd(&deg[dst[e]], 1);
}

__global__ __launch_bounds__(1024) void scan_block_k(const int* __restrict__ deg,
                                                     int* __restrict__ row_ptr,
                                                     int* __restrict__ bsum, int n) {
  __shared__ int sm[1024];
  int i = blockIdx.x * 1024 + threadIdx.x;
  int v = (i < n) ? deg[i] : 0;
  sm[threadIdx.x] = v;
  __syncthreads();
  for (int off = 1; off < 1024; off <<= 1) {
    int t = (threadIdx.x >= off) ? sm[threadIdx.x - off] : 0;
    __syncthreads();
    sm[threadIdx.x] += t;
    __syncthreads();
  }
  if (i < n) row_ptr[1 + i] = sm[threadIdx.x];
  if (threadIdx.x == 1023) bsum[blockIdx.x] = sm[1023];
}

__global__ void scan_sums_k(int* bsum, int nb) {
  if (threadIdx.x == 0 && blockIdx.x == 0) {
    int run = 0;
    for (int i = 0; i < nb; ++i) { int t = bsum[i]; bsum[i] = run; run += t; }
  }
}

__global__ __launch_bounds__(256) void scan_add_k(int* __restrict__ row_ptr, const int* __restrict__ bsum, int n) {
  int i = blockIdx.x * 256 + threadIdx.x;
  if (i < n) row_ptr[1 + i] += bsum[i / 1024];
  if (i == 0) row_ptr[0] = 0;
}

__global__ __launch_bounds__(256) void pos_init_k(int* __restrict__ pos, const int* __restrict__ row_ptr, int n) {
  int i = blockIdx.x * 256 + threadIdx.x;
  if (i < n) pos[i] = row_ptr[i];
}

__global__ __launch_bounds__(256) void scatter_k(const int* __restrict__ src, const int* __restrict__ dst,
                                                 int* __restrict__ pos, int* __restrict__ esrc, int E) {
  int e = blockIdx.x * 256 + threadIdx.x;
  if (e < E) {
    int slot = atomicAdd(&pos[dst[e]], 1);
    esrc[slot] = src[e];
  }
}

// ------------------- MFMA fp16 GEMM (layer 1: feats @ W1 -> h1 fp16) -------
// C[M,Ncols] = A[M,K]fp32 @ B[K,Ncols]fp32, inputs converted to fp16 in
// staging, fp32 accumulate, fp16 output. BM=BN=128, BK=32, 4 waves, each wave
// 64x64 (4x4 frags of 16x16x32). LDS rows padded to 40 halves (80B stride:
// 2-way bank aliasing only, free per m136).
__global__ __launch_bounds__(256) void gemm_mfma_k(const float* __restrict__ A,
                                                   const float* __restrict__ B,
                                                   __half* __restrict__ C,
                                                   int M, int Ncols, int K) {
  constexpr int BM = 128, BN = 128, BK = 32, PAD = 40;
  __shared__ alignas(16) _Float16 A_lds[BM][PAD];   // [row][k]
  __shared__ alignas(16) _Float16 B_lds[BN][PAD];   // [col][k] (transposed)
  const int tid  = threadIdx.x;
  const int lane = tid & 63;
  const int wave = tid >> 6;
  const int wr = wave >> 1, wc = wave & 1;          // 2x2 wave grid
  const int row0 = blockIdx.y * BM;
  const int col0 = blockIdx.x * BN;
  const int l15 = lane & 15;
  const int lch = lane >> 4;                        // k-chunk 0..3

  f32x4 acc[4][4];
  #pragma unroll
  for (int m = 0; m < 4; ++m)
    #pragma unroll
    for (int n = 0; n < 4; ++n) acc[m][n] = (f32x4){0.f, 0.f, 0.f, 0.f};

  for (int k0 = 0; k0 < K; k0 += BK) {
    // A tile: 128x32 fp32 = 1024 float4; 4 per thread; convert to fp16
    #pragma unroll
    for (int it = 0; it < 4; ++it) {
      int f4 = tid + it * 256;
      int row = f4 >> 3;
      int k = (f4 & 7) * 4;
      int grow = row0 + row;
      float4 v = make_float4(0.f, 0.f, 0.f, 0.f);
      if (grow < M) v = *(const float4*)(A + (size_t)grow * K + k0 + k);
      f16x4 hv = {(_Float16)v.x, (_Float16)v.y, (_Float16)v.z, (_Float16)v.w};
      *(f16x4*)&A_lds[row][k] = hv;
    }
    // B tile: 32x128 fp32, store transposed [col][k]
    #pragma unroll
    for (int it = 0; it < 4; ++it) {
      int f4 = tid + it * 256;
      int kk = f4 >> 5;
      int col = (f4 & 31) * 4;
      float4 v = *(const float4*)(B + (size_t)(k0 + kk) * Ncols + col0 + col);
      B_lds[col + 0][kk] = (_Float16)v.x;
      B_lds[col + 1][kk] = (_Float16)v.y;
      B_lds[col + 2][kk] = (_Float16)v.z;
      B_lds[col + 3][kk] = (_Float16)v.w;
    }
    __syncthreads();

    f16x8 a[4], b[4];
    #pragma unroll
    for (int m = 0; m < 4; ++m)
      a[m] = *(const f16x8*)&A_lds[wr * 64 + m * 16 + l15][lch * 8];
    #pragma unroll
    for (int n = 0; n < 4; ++n)
      b[n] = *(const f16x8*)&B_lds[wc * 64 + n * 16 + l15][lch * 8];
    #pragma unroll
    for (int m = 0; m < 4; ++m)
      #pragma unroll
      for (int n = 0; n < 4; ++n)
        acc[m][n] = __builtin_amdgcn_mfma_f32_16x16x32_f16(a[m], b[n], acc[m][n], 0, 0, 0);
    __syncthreads();
  }

  // C/D layout: col = lane&15, row = (lane>>4)*4 + reg   [m89/m91 verified]
  _Float16* Ch = (_Float16*)C;
  #pragma unroll
  for (int m = 0; m < 4; ++m) {
    #pragma unroll
    for (int r = 0; r < 4; ++r) {
      int grow = row0 + wr * 64 + m * 16 + lch * 4 + r;
      if (grow < M) {
        #pragma unroll
        for (int n = 0; n < 4; ++n) {
          int gcol = col0 + wc * 64 + n * 16 + l15;
          Ch[(size_t)grow * Ncols + gcol] = (_Float16)acc[m][n][r];
        }
      }
    }
  }
}

// ---------------------------- fp32 GEMM (layer 2) ---------------------------

template <int BN, int TN, bool HOUT>
__global__ __launch_bounds__(256) void gemm_f32_k(const float* __restrict__ A,
                                                  const float* __restrict__ B,
                                                  void* __restrict__ Cv,
                                                  int M, int N, int K) {
  constexpr int BM = 128, BK = 16, TM = 8;
  __shared__ float As[BK][BM + 4];
  __shared__ float Bs[BK][BN];
  const int tid = threadIdx.x;
  const int tx = tid & 15;
  const int ty = tid >> 4;
  const int row0 = blockIdx.x * BM;
  const int col0 = blockIdx.y * BN;

  float acc[TM][TN];
  #pragma unroll
  for (int i = 0; i < TM; ++i)
    #pragma unroll
    for (int j = 0; j < TN; ++j) acc[i][j] = 0.f;

  for (int k0 = 0; k0 < K; k0 += BK) {
    #pragma unroll
    for (int it = 0; it < (BM * BK / 4) / 256; ++it) {
      int f4 = tid + it * 256;
      int row = f4 >> 2;
      int c4 = f4 & 3;
      int grow = row0 + row;
      float4 v = make_float4(0.f, 0.f, 0.f, 0.f);
      if (grow < M) v = *(const float4*)(A + (size_t)grow * K + k0 + c4 * 4);
      As[c4 * 4 + 0][row] = v.x;
      As[c4 * 4 + 1][row] = v.y;
      As[c4 * 4 + 2][row] = v.z;
      As[c4 * 4 + 3][row] = v.w;
    }
    #pragma unroll
    for (int it = 0; it < (BK * BN / 4) / 256; ++it) {
      int f4 = tid + it * 256;
      int kk = f4 / (BN / 4);
      int n4 = f4 % (BN / 4);
      *(float4*)&Bs[kk][n4 * 4] = *(const float4*)(B + (size_t)(k0 + kk) * N + col0 + n4 * 4);
    }
    __syncthreads();
    #pragma unroll
    for (int kk = 0; kk < BK; ++kk) {
      float a[TM], b[TN];
      float4 a0 = *(const float4*)&As[kk][ty * TM];
      float4 a1 = *(const float4*)&As[kk][ty * TM + 4];
      a[0] = a0.x; a[1] = a0.y; a[2] = a0.z; a[3] = a0.w;
      a[4] = a1.x; a[5] = a1.y; a[6] = a1.z; a[7] = a1.w;
      #pragma unroll
      for (int j = 0; j < TN; j += 4) {
        float4 bv = *(const float4*)&Bs[kk][tx * TN + j];
        b[j] = bv.x; b[j + 1] = bv.y; b[j + 2] = bv.z; b[j + 3] = bv.w;
      }
      #pragma unroll
      for (int i = 0; i < TM; ++i)
        #pragma unroll
        for (int j = 0; j < TN; ++j) acc[i][j] = fmaf(a[i], b[j], acc[i][j]);
    }
    __syncthreads();
  }
  #pragma unroll
  for (int i = 0; i < TM; ++i) {
    int grow = row0 + ty * TM + i;
    if (grow < M) {
      #pragma unroll
      for (int j = 0; j < TN; j += 4) {
        if constexpr (HOUT) {
          __half2 p0 = __floats2half2_rn(acc[i][j], acc[i][j + 1]);
          __half2 p1 = __floats2half2_rn(acc[i][j + 2], acc[i][j + 3]);
          uint2 u;
          u.x = *(unsigned int*)&p0;
          u.y = *(unsigned int*)&p1;
          *(uint2*)((__half*)Cv + (size_t)grow * N + col0 + tx * TN + j) = u;
        } else {
          float4 v = make_float4(acc[i][j], acc[i][j + 1], acc[i][j + 2], acc[i][j + 3]);
          *(float4*)((float*)Cv + (size_t)grow * N + col0 + tx * TN + j) = v;
        }
      }
    }
  }
}

// ------------------------- attention dot products --------------------------

__global__ __launch_bounds__(256) void elr1_k(const __half* __restrict__ h1,
                                              const float* __restrict__ al,
                                              const float* __restrict__ ar,
                                              float* __restrict__ el, float* __restrict__ er, int N) {
  int wave = blockIdx.x * 4 + (threadIdx.x >> 6);
  int lane = threadIdx.x & 63;
  if (wave >= N) return;
  float alv[8], arv[8];
  #pragma unroll
  for (int h = 0; h < 8; ++h) { alv[h] = al[h * 64 + lane]; arv[h] = ar[h * 64 + lane]; }
  const __half* hr = h1 + (size_t)wave * 512 + lane;
  float se[8], sr[8];
  #pragma unroll
  for (int h = 0; h < 8; ++h) {
    float v = __half2float(hr[h * 64]);
    se[h] = v * alv[h];
    sr[h] = v * arv[h];
  }
  #pragma unroll
  for (int off = 32; off; off >>= 1) {
    #pragma unroll
    for (int h = 0; h < 8; ++h) {
      se[h] += __shfl_xor(se[h], off);
      sr[h] += __shfl_xor(sr[h], off);
    }
  }
  if (lane == 0) {
    #pragma unroll
    for (int h = 0; h < 8; ++h) {
      el[(size_t)wave * 8 + h] = se[h];
      er[(size_t)wave * 8 + h] = sr[h];
    }
  }
}

__global__ __launch_bounds__(256) void elr2_k(const float* __restrict__ h2,
                                              const float* __restrict__ al,
                                              const float* __restrict__ ar,
                                              float* __restrict__ el, float* __restrict__ er, int N) {
  int wave = blockIdx.x * 4 + (threadIdx.x >> 6);
  int lane = threadIdx.x & 63;
  if (wave >= N) return;
  float v = h2[(size_t)wave * 64 + lane];
  float sl = v * al[lane];
  float sr = v * ar[lane];
  sl = wred_sum(sl);
  sr = wred_sum(sr);
  if (lane == 0) { el[wave] = sl; er[wave] = sr; }
}

// ------------------------- aggregation (edge softmax + SpMM) ----------------

__global__ __launch_bounds__(256) void agg1_k(const __half* __restrict__ h1,
                                              const float* __restrict__ el,
                                              const float* __restrict__ er,
                                              const int* __restrict__ row_ptr,
                                              const int* __restrict__ esrc,
                                              const float* __restrict__ b1,
                                              float* __restrict__ x2, int N) {
  __shared__ float p_lds[4][64][4];
  __shared__ int   s_lds[4][64];
  const int widx = threadIdx.x >> 6;
  const int lane = threadIdx.x & 63;
  const int gw = blockIdx.x * 4 + widx;
  const int n = gw >> 1;
  const int half = gw & 1;
  if (n >= N) return;
  const int start = row_ptr[n], end = row_ptr[n + 1];
  const int hg = lane >> 4;

  float4 er4 = *(const float4*)(er + (size_t)n * 8 + half * 4);
  float erh[4] = {er4.x, er4.y, er4.z, er4.w};

  float4 acc = make_float4(0.f, 0.f, 0.f, 0.f);
  float m[4], denom[4];
  #pragma unroll
  for (int h = 0; h < 4; ++h) { m[h] = -INFINITY; denom[h] = 0.f; }

  for (int base = start; base < end; base += 64) {
    int j = base + lane;
    bool valid = j < end;
    int s = valid ? esrc[j] : 0;

    float4 e4 = *(const float4*)(el + (size_t)s * 8 + half * 4);
    float sc[4];
    sc[0] = lrelu(e4.x + erh[0]); sc[1] = lrelu(e4.y + erh[1]);
    sc[2] = lrelu(e4.z + erh[2]); sc[3] = lrelu(e4.w + erh[3]);
    if (!valid) { sc[0] = sc[1] = sc[2] = sc[3] = -INFINITY; }

    float p[4], fs[4];
    #pragma unroll
    for (int h = 0; h < 4; ++h) {
      float bm = wred_max(sc[h]);
      float nm = fmaxf(m[h], bm);
      fs[h] = expf(m[h] - nm);
      m[h] = nm;
      p[h] = valid ? expf(sc[h] - nm) : 0.f;
      denom[h] = denom[h] * fs[h] + wred_sum(p[h]);
    }
    float fmine = hg == 0 ? fs[0] : hg == 1 ? fs[1] : hg == 2 ? fs[2] : fs[3];
    acc.x *= fmine; acc.y *= fmine; acc.z *= fmine; acc.w *= fmine;

    *(float4*)&p_lds[widx][lane][0] = make_float4(p[0], p[1], p[2], p[3]);
    s_lds[widx][lane] = s;

    const int cnt = min(64, end - base);
    const __half* __restrict__ hbase = h1 + (size_t)half * 256 + lane * 4;
    int jj = 0;
    for (; jj + 4 <= cnt; jj += 4) {
      int   ss[4];
      float a[4];
      uint2 hv[4];
      #pragma unroll
      for (int u = 0; u < 4; ++u) ss[u] = s_lds[widx][jj + u];
      #pragma unroll
      for (int u = 0; u < 4; ++u) a[u] = p_lds[widx][jj + u][hg];
      #pragma unroll
      for (int u = 0; u < 4; ++u) hv[u] = *(const uint2*)(hbase + (size_t)ss[u] * 512);
      #pragma unroll
      for (int u = 0; u < 4; ++u) {
        float2 f01 = __half22float2(*(__half2*)&hv[u].x);
        float2 f23 = __half22float2(*(__half2*)&hv[u].y);
        acc.x = fmaf(a[u], f01.x, acc.x);
        acc.y = fmaf(a[u], f01.y, acc.y);
        acc.z = fmaf(a[u], f23.x, acc.z);
        acc.w = fmaf(a[u], f23.y, acc.w);
      }
    }
    for (; jj < cnt; ++jj) {
      int ss = s_lds[widx][jj];
      float a = p_lds[widx][jj][hg];
      uint2 hv = *(const uint2*)(hbase + (size_t)ss * 512);
      float2 f01 = __half22float2(*(__half2*)&hv.x);
      float2 f23 = __half22float2(*(__half2*)&hv.y);
      acc.x = fmaf(a, f01.x, acc.x);
      acc.y = fmaf(a, f01.y, acc.y);
      acc.z = fmaf(a, f23.x, acc.z);
      acc.w = fmaf(a, f23.y, acc.w);
    }
  }

  const int deg = end - start;
  float dh = hg == 0 ? denom[0] : hg == 1 ? denom[1] : hg == 2 ? denom[2] : denom[3];
  float inv = deg ? 1.f / dh : 0.f;
  float4 bv = *(const float4*)(b1 + half * 256 + lane * 4);
  float4 o;
  o.x = fmaxf(acc.x * inv + bv.x, 0.f);
  o.y = fmaxf(acc.y * inv + bv.y, 0.f);
  o.z = fmaxf(acc.z * inv + bv.z, 0.f);
  o.w = fmaxf(acc.w * inv + bv.w, 0.f);
  *(float4*)(x2 + (size_t)n * 512 + half * 256 + lane * 4) = o;
}

__global__ __launch_bounds__(256) void agg2_k(const float* __restrict__ h2,
                                              const float* __restrict__ el,
                                              const float* __restrict__ er,
                                              const int* __restrict__ row_ptr,
                                              const int* __restrict__ esrc,
                                              const float* __restrict__ b2,
                                              float* __restrict__ out, int N) {
  __shared__ float p_lds[4][64];
  __shared__ int   s_lds[4][64];
  const int widx = threadIdx.x >> 6;
  const int lane = threadIdx.x & 63;
  const int n = blockIdx.x * 4 + widx;
  if (n >= N) return;
  const int start = row_ptr[n], end = row_ptr[n + 1];
  const int eg = lane >> 4;
  const int dg = lane & 15;
  const float ern = er[n];

  float4 acc = make_float4(0.f, 0.f, 0.f, 0.f);
  float m = -INFINITY, denom = 0.f;

  for (int base = start; base < end; base += 64) {
    int j = base + lane;
    bool valid = j < end;
    int s = valid ? esrc[j] : 0;
    float sc = valid ? lrelu(el[s] + ern) : -INFINITY;
    float bm = wred_max(sc);
    float nm = fmaxf(m, bm);
    float f = expf(m - nm);
    m = nm;
    float p = valid ? expf(sc - nm) : 0.f;
    denom = denom * f + wred_sum(p);
    acc.x *= f; acc.y *= f; acc.z *= f; acc.w *= f;

    p_lds[widx][lane] = p;
    s_lds[widx][lane] = s;

    const int cnt = min(64, end - base);
    for (int jj = 0; jj < cnt; jj += 4) {
      int myj = jj + eg;
      bool v2 = myj < cnt;
      int ss = s_lds[widx][v2 ? myj : 0];
      float a = v2 ? p_lds[widx][myj] : 0.f;
      float4 hv = *(const float4*)(h2 + (size_t)ss * 64 + dg * 4);
      acc.x = fmaf(a, hv.x, acc.x);
      acc.y = fmaf(a, hv.y, acc.y);
      acc.z = fmaf(a, hv.z, acc.z);
      acc.w = fmaf(a, hv.w, acc.w);
    }
  }

  #pragma unroll
  for (int off = 16; off <= 32; off <<= 1) {
    acc.x += __shfl_xor(acc.x, off);
    acc.y += __shfl_xor(acc.y, off);
    acc.z += __shfl_xor(acc.z, off);
    acc.w += __shfl_xor(acc.w, off);
  }

  if (eg == 0) {
    const int deg = end - start;
    float inv = deg ? 1.f / denom : 0.f;
    float4 bv = *(const float4*)(b2 + dg * 4);
    float4 o;
    o.x = acc.x * inv + bv.x;
    o.y = acc.y * inv + bv.y;
    o.z = acc.z * inv + bv.z;
    o.w = acc.w * inv + bv.w;
    *(float4*)(out + (size_t)n * 64 + dg * 4) = o;
  }
}

// ---------------------------------------------------------------------------

extern "C" void kernel_launch(void* const* d_in, const int* in_sizes, int n_in,
                              void* d_out, int out_size, void* d_ws, size_t ws_size,
                              hipStream_t stream) {
  const float* feats = (const float*)d_in[0];
  const float* W1    = (const float*)d_in[1];
  const float* al1   = (const float*)d_in[2];
  const float* ar1   = (const float*)d_in[3];
  const float* b1    = (const float*)d_in[4];
  const float* W2    = (const float*)d_in[5];
  const float* al2   = (const float*)d_in[6];
  const float* ar2   = (const float*)d_in[7];
  const float* b2    = (const float*)d_in[8];
  const int*   src   = (const int*)d_in[9];
  const int*   dst   = (const int*)d_in[10];

  const int N = in_sizes[0] / 256;   // 50000
  const int E = in_sizes[9];         // 800000
  const int IN = 256, HD1 = 512, D2 = 64;

  char* w = (char*)d_ws;
  size_t off = 0;
  auto alloc = [&](size_t bytes) -> void* {
    void* p = w + off;
    off = (off + bytes + 255) & ~(size_t)255;
    return p;
  };
  __half* h1h    = (__half*)alloc((size_t)N * HD1 * 2);
  float* x2      = (float*)alloc((size_t)N * HD1 * 4);
  float* h2      = (float*)alloc((size_t)N * D2 * 4);
  float* el1     = (float*)alloc((size_t)N * 8 * 4);
  float* er1     = (float*)alloc((size_t)N * 8 * 4);
  float* el2     = (float*)alloc((size_t)N * 4);
  float* er2     = (float*)alloc((size_t)N * 4);
  int*   deg     = (int*)alloc((size_t)N * 4);
  int*   row_ptr = (int*)alloc((size_t)(N + 1) * 4);
  int*   pos     = (int*)alloc((size_t)N * 4);
  int*   bsum    = (int*)alloc(64 * 4);
  int*   esrc    = (int*)alloc((size_t)E * 4);

  float* outp = (float*)d_out;

  const int NB_E   = (E + 255) / 256;
  const int NB_N   = (N + 255) / 256;
  const int NB_SC  = (N + 1023) / 1024;
  const int NB_W4  = (N + 3) / 4;
  const int NB_AG1 = (2 * N + 3) / 4;

  // ---- CSR build (dst-sorted src list), shared by both layers
  hipMemsetAsync(deg, 0, (size_t)N * 4, stream);
  hist_k<<<NB_E, 256, 0, stream>>>(dst, deg, E);
  scan_block_k<<<NB_SC, 1024, 0, stream>>>(deg, row_ptr, bsum, N);
  scan_sums_k<<<1, 64, 0, stream>>>(bsum, NB_SC);
  scan_add_k<<<NB_N, 256, 0, stream>>>(row_ptr, bsum, N);
  pos_init_k<<<NB_N, 256, 0, stream>>>(pos, row_ptr, N);
  scatter_k<<<NB_E, 256, 0, stream>>>(src, dst, pos, esrc, E);

  // ---- layer 1: MFMA fp16 GEMM -> h1 fp16
  {
    dim3 g(HD1 / 128, (N + 127) / 128);   // col-block fastest: A rows L2-reused
    gemm_mfma_k<<<g, 256, 0, stream>>>(feats, W1, h1h, N, HD1, IN);
  }
  elr1_k<<<NB_W4, 256, 0, stream>>>(h1h, al1, ar1, el1, er1, N);
  agg1_k<<<NB_AG1, 256, 0, stream>>>(h1h, el1, er1, row_ptr, esrc, b1, x2, N);

  // ---- layer 2
  {
    dim3 g((N + 127) / 128, D2 / 64);
    gemm_f32_k<64, 4, false><<<g, 256, 0, stream>>>(x2, W2, h2, N, D2, HD1);
  }
  elr2_k<<<NB_W4, 256, 0, stream>>>(h2, al2, ar2, el2, er2, N);
  agg2_k<<<NB_W4, 256, 0, stream>>>(h2, el2, er2, row_ptr, esrc, b2, outp, N);
}

// Round 12
// 502.328 us; speedup vs baseline: 1.5559x; 1.1578x over previous
//
#include <hip/hip_runtime.h>
#include <hip/hip_bf16.h>
#include <hip/hip_fp16.h>
#include <math.h>

// ---------------------------------------------------------------------------
// GAT 2-layer forward. N=50000 nodes, E=800000 edges, 256 in-feats,
// layer1: 8 heads x 64, layer2: 1 head x 64.
// All inter-kernel activations (h1, x2, h2) stored fp16: the edge gathers are
// L2-miss-BW-bound (8 XCDs replicate the node table; measured 3.8 TB/s wall),
// so bytes are the lever (r7: fp16 h1 halved FETCH 819->418MB, -107us).
// GEMMs are fp16-input MFMA (mfma_f32_16x16x32_f16, fp32 acc), weights
// pre-converted to fp16 transposed [col][K] once per launch. LDS uses 16B
// chunks XOR-swizzled by (row&7): 2-way bank aliasing only (free, m136).
// ---------------------------------------------------------------------------

#define NEG_SLOPE 0.2f

typedef _Float16 f16x8 __attribute__((ext_vector_type(8)));
typedef float f32x4 __attribute__((ext_vector_type(4)));

__device__ __forceinline__ float lrelu(float x) { return x >= 0.f ? x : NEG_SLOPE * x; }

__device__ __forceinline__ float wred_max(float v) {
  #pragma unroll
  for (int off = 32; off; off >>= 1) v = fmaxf(v, __shfl_xor(v, off));
  return v;
}
__device__ __forceinline__ float wred_sum(float v) {
  #pragma unroll
  for (int off = 32; off; off >>= 1) v += __shfl_xor(v, off);
  return v;
}

// ---------------------------- CSR build ------------------------------------

__global__ __launch_bounds__(256) void hist_k(const int* __restrict__ dst, int* __restrict__ deg, int E) {
  int e = blockIdx.x * 256 + threadIdx.x;
  if (e < E) atomicAdd(&deg[dst[e]], 1);
}

__global__ __launch_bounds__(1024) void scan_block_k(const int* __restrict__ deg,
                                                     int* __restrict__ row_ptr,
                                                     int* __restrict__ bsum, int n) {
  __shared__ int sm[1024];
  int i = blockIdx.x * 1024 + threadIdx.x;
  int v = (i < n) ? deg[i] : 0;
  sm[threadIdx.x] = v;
  __syncthreads();
  for (int off = 1; off < 1024; off <<= 1) {
    int t = (threadIdx.x >= off) ? sm[threadIdx.x - off] : 0;
    __syncthreads();
    sm[threadIdx.x] += t;
    __syncthreads();
  }
  if (i < n) row_ptr[1 + i] = sm[threadIdx.x];
  if (threadIdx.x == 1023) bsum[blockIdx.x] = sm[1023];
}

__global__ void scan_sums_k(int* bsum, int nb) {
  if (threadIdx.x == 0 && blockIdx.x == 0) {
    int run = 0;
    for (int i = 0; i < nb; ++i) { int t = bsum[i]; bsum[i] = run; run += t; }
  }
}

__global__ __launch_bounds__(256) void scan_add_k(int* __restrict__ row_ptr, const int* __restrict__ bsum, int n) {
  int i = blockIdx.x * 256 + threadIdx.x;
  if (i < n) row_ptr[1 + i] += bsum[i / 1024];
  if (i == 0) row_ptr[0] = 0;
}

__global__ __launch_bounds__(256) void pos_init_k(int* __restrict__ pos, const int* __restrict__ row_ptr, int n) {
  int i = blockIdx.x * 256 + threadIdx.x;
  if (i < n) pos[i] = row_ptr[i];
}

__global__ __launch_bounds__(256) void scatter_k(const int* __restrict__ src, const int* __restrict__ dst,
                                                 int* __restrict__ pos, int* __restrict__ esrc, int E) {
  int e = blockIdx.x * 256 + threadIdx.x;
  if (e < E) {
    int slot = atomicAdd(&pos[dst[e]], 1);
    esrc[slot] = src[e];
  }
}

// ---------------- weight convert+transpose: W[K][Nc] -> Wt[Nc][K] fp16 ------

__global__ __launch_bounds__(256) void cvt_t_k(const float* __restrict__ W,
                                               __half* __restrict__ Wt, int K, int Nc) {
  int idx = blockIdx.x * 256 + threadIdx.x;
  if (idx < K * Nc) {
    int c = idx / K;
    int k = idx - c * K;           // k fastest -> coalesced writes
    Wt[(size_t)c * K + k] = __float2half(W[(size_t)k * Nc + c]);
  }
}

// ------------------- MFMA fp16 GEMM template --------------------------------
// C[M,Nc](fp16) = A[M,K] @ Bt[Nc][K](fp16). AF32: A is fp32 (converted in
// staging), else fp16. BM=128, BK=128, 4 waves (2x2), wave = 64 x BN/2.
// LDS in 16B chunks (f16x8), chunk index XOR-swizzled by (row&7): write and
// read use the same involution -> 2-way bank conflicts only.

template <int BN, bool AF32>
__global__ __launch_bounds__(256) void gemm16_k(const void* __restrict__ Av,
                                                const __half* __restrict__ Bt,
                                                __half* __restrict__ C,
                                                int M, int Nc, int K) {
  constexpr int BM = 128, BK = 128;
  constexpr int NF = BN / 32;          // frags per wave in N
  constexpr int ACH = BK / 8;          // 16B chunks per row (=16)
  __shared__ f16x8 A_lds[BM * ACH];
  __shared__ f16x8 B_lds[BN * ACH];
  const int tid = threadIdx.x;
  const int lane = tid & 63;
  const int wave = tid >> 6;
  const int wr = wave >> 1, wc = wave & 1;
  const int l15 = lane & 15, lch = lane >> 4;
  const int row0 = blockIdx.y * BM;
  const int col0 = blockIdx.x * BN;

  f32x4 acc[4][NF];
  #pragma unroll
  for (int m = 0; m < 4; ++m)
    #pragma unroll
    for (int n = 0; n < NF; ++n) acc[m][n] = (f32x4){0.f, 0.f, 0.f, 0.f};

  for (int k0 = 0; k0 < K; k0 += BK) {
    // stage A: BM rows x 16 chunks
    #pragma unroll
    for (int it = 0; it < BM * ACH / 256; ++it) {
      int cidx = tid + it * 256;
      int row = cidx >> 4, ch = cidx & 15;
      int grow = row0 + row;
      f16x8 hv = {};
      if (grow < M) {
        if constexpr (AF32) {
          const float* p = (const float*)Av + (size_t)grow * K + k0 + ch * 8;
          float4 v0 = *(const float4*)p;
          float4 v1 = *(const float4*)(p + 4);
          hv = (f16x8){(_Float16)v0.x, (_Float16)v0.y, (_Float16)v0.z, (_Float16)v0.w,
                       (_Float16)v1.x, (_Float16)v1.y, (_Float16)v1.z, (_Float16)v1.w};
        } else {
          hv = *(const f16x8*)((const __half*)Av + (size_t)grow * K + k0 + ch * 8);
        }
      }
      A_lds[row * ACH + (ch ^ (row & 7))] = hv;
    }
    // stage B: BN cols x 16 chunks (Bt is [col][K] fp16, contiguous)
    #pragma unroll
    for (int it = 0; it < BN * ACH / 256; ++it) {
      int cidx = tid + it * 256;
      int col = cidx >> 4, ch = cidx & 15;
      B_lds[col * ACH + (ch ^ (col & 7))] =
          *(const f16x8*)(Bt + (size_t)(col0 + col) * K + k0 + ch * 8);
    }
    __syncthreads();
    #pragma unroll
    for (int ksub = 0; ksub < 4; ++ksub) {
      f16x8 a[4], b[NF];
      #pragma unroll
      for (int m = 0; m < 4; ++m) {
        int R = wr * 64 + m * 16 + l15;
        a[m] = A_lds[R * ACH + ((ksub * 4 + lch) ^ (R & 7))];
      }
      #pragma unroll
      for (int n = 0; n < NF; ++n) {
        int Cc = wc * (BN / 2) + n * 16 + l15;
        b[n] = B_lds[Cc * ACH + ((ksub * 4 + lch) ^ (Cc & 7))];
      }
      #pragma unroll
      for (int m = 0; m < 4; ++m)
        #pragma unroll
        for (int n = 0; n < NF; ++n)
          acc[m][n] = __builtin_amdgcn_mfma_f32_16x16x32_f16(a[m], b[n], acc[m][n], 0, 0, 0);
    }
    __syncthreads();
  }

  // C/D layout: col = lane&15, row = (lane>>4)*4 + reg  [m89/m91; r8-verified]
  #pragma unroll
  for (int m = 0; m < 4; ++m) {
    #pragma unroll
    for (int r = 0; r < 4; ++r) {
      int grow = row0 + wr * 64 + m * 16 + lch * 4 + r;
      if (grow < M) {
        #pragma unroll
        for (int n = 0; n < NF; ++n) {
          int gcol = col0 + wc * (BN / 2) + n * 16 + l15;
          C[(size_t)grow * Nc + gcol] = __float2half(acc[m][n][r]);
        }
      }
    }
  }
}

// ------------------------- attention dot products --------------------------

__global__ __launch_bounds__(256) void elr1_k(const __half* __restrict__ h1,
                                              const float* __restrict__ al,
                                              const float* __restrict__ ar,
                                              float* __restrict__ el, float* __restrict__ er, int N) {
  int wave = blockIdx.x * 4 + (threadIdx.x >> 6);
  int lane = threadIdx.x & 63;
  if (wave >= N) return;
  float alv[8], arv[8];
  #pragma unroll
  for (int h = 0; h < 8; ++h) { alv[h] = al[h * 64 + lane]; arv[h] = ar[h * 64 + lane]; }
  const __half* hr = h1 + (size_t)wave * 512 + lane;
  float se[8], sr[8];
  #pragma unroll
  for (int h = 0; h < 8; ++h) {
    float v = __half2float(hr[h * 64]);
    se[h] = v * alv[h];
    sr[h] = v * arv[h];
  }
  #pragma unroll
  for (int off = 32; off; off >>= 1) {
    #pragma unroll
    for (int h = 0; h < 8; ++h) {
      se[h] += __shfl_xor(se[h], off);
      sr[h] += __shfl_xor(sr[h], off);
    }
  }
  if (lane == 0) {
    #pragma unroll
    for (int h = 0; h < 8; ++h) {
      el[(size_t)wave * 8 + h] = se[h];
      er[(size_t)wave * 8 + h] = sr[h];
    }
  }
}

__global__ __launch_bounds__(256) void elr2_k(const __half* __restrict__ h2,
                                              const float* __restrict__ al,
                                              const float* __restrict__ ar,
                                              float* __restrict__ el, float* __restrict__ er, int N) {
  int wave = blockIdx.x * 4 + (threadIdx.x >> 6);
  int lane = threadIdx.x & 63;
  if (wave >= N) return;
  float v = __half2float(h2[(size_t)wave * 64 + lane]);
  float sl = v * al[lane];
  float sr = v * ar[lane];
  sl = wred_sum(sl);
  sr = wred_sum(sr);
  if (lane == 0) { el[wave] = sl; er[wave] = sr; }
}

// ------------------------- aggregation (edge softmax + SpMM) ----------------

// layer1: 2 waves per node; wave = 4 heads (half*256..+256 dims); fp16 gather
// (8B/lane/edge); x2 written fp16 (feeds MFMA gemm2 directly).
__global__ __launch_bounds__(256) void agg1_k(const __half* __restrict__ h1,
                                              const float* __restrict__ el,
                                              const float* __restrict__ er,
                                              const int* __restrict__ row_ptr,
                                              const int* __restrict__ esrc,
                                              const float* __restrict__ b1,
                                              __half* __restrict__ x2, int N) {
  __shared__ float p_lds[4][64][4];
  __shared__ int   s_lds[4][64];
  const int widx = threadIdx.x >> 6;
  const int lane = threadIdx.x & 63;
  const int gw = blockIdx.x * 4 + widx;
  const int n = gw >> 1;
  const int half = gw & 1;
  if (n >= N) return;
  const int start = row_ptr[n], end = row_ptr[n + 1];
  const int hg = lane >> 4;

  float4 er4 = *(const float4*)(er + (size_t)n * 8 + half * 4);
  float erh[4] = {er4.x, er4.y, er4.z, er4.w};

  float4 acc = make_float4(0.f, 0.f, 0.f, 0.f);
  float m[4], denom[4];
  #pragma unroll
  for (int h = 0; h < 4; ++h) { m[h] = -INFINITY; denom[h] = 0.f; }

  for (int base = start; base < end; base += 64) {
    int j = base + lane;
    bool valid = j < end;
    int s = valid ? esrc[j] : 0;

    float4 e4 = *(const float4*)(el + (size_t)s * 8 + half * 4);
    float sc[4];
    sc[0] = lrelu(e4.x + erh[0]); sc[1] = lrelu(e4.y + erh[1]);
    sc[2] = lrelu(e4.z + erh[2]); sc[3] = lrelu(e4.w + erh[3]);
    if (!valid) { sc[0] = sc[1] = sc[2] = sc[3] = -INFINITY; }

    float p[4], fs[4];
    #pragma unroll
    for (int h = 0; h < 4; ++h) {
      float bm = wred_max(sc[h]);
      float nm = fmaxf(m[h], bm);
      fs[h] = expf(m[h] - nm);
      m[h] = nm;
      p[h] = valid ? expf(sc[h] - nm) : 0.f;
      denom[h] = denom[h] * fs[h] + wred_sum(p[h]);
    }
    float fmine = hg == 0 ? fs[0] : hg == 1 ? fs[1] : hg == 2 ? fs[2] : fs[3];
    acc.x *= fmine; acc.y *= fmine; acc.z *= fmine; acc.w *= fmine;

    *(float4*)&p_lds[widx][lane][0] = make_float4(p[0], p[1], p[2], p[3]);
    s_lds[widx][lane] = s;

    const int cnt = min(64, end - base);
    const __half* __restrict__ hbase = h1 + (size_t)half * 256 + lane * 4;
    int jj = 0;
    for (; jj + 4 <= cnt; jj += 4) {
      int   ss[4];
      float a[4];
      uint2 hv[4];
      #pragma unroll
      for (int u = 0; u < 4; ++u) ss[u] = s_lds[widx][jj + u];
      #pragma unroll
      for (int u = 0; u < 4; ++u) a[u] = p_lds[widx][jj + u][hg];
      #pragma unroll
      for (int u = 0; u < 4; ++u) hv[u] = *(const uint2*)(hbase + (size_t)ss[u] * 512);
      #pragma unroll
      for (int u = 0; u < 4; ++u) {
        float2 f01 = __half22float2(*(__half2*)&hv[u].x);
        float2 f23 = __half22float2(*(__half2*)&hv[u].y);
        acc.x = fmaf(a[u], f01.x, acc.x);
        acc.y = fmaf(a[u], f01.y, acc.y);
        acc.z = fmaf(a[u], f23.x, acc.z);
        acc.w = fmaf(a[u], f23.y, acc.w);
      }
    }
    for (; jj < cnt; ++jj) {
      int ss = s_lds[widx][jj];
      float a = p_lds[widx][jj][hg];
      uint2 hv = *(const uint2*)(hbase + (size_t)ss * 512);
      float2 f01 = __half22float2(*(__half2*)&hv.x);
      float2 f23 = __half22float2(*(__half2*)&hv.y);
      acc.x = fmaf(a, f01.x, acc.x);
      acc.y = fmaf(a, f01.y, acc.y);
      acc.z = fmaf(a, f23.x, acc.z);
      acc.w = fmaf(a, f23.y, acc.w);
    }
  }

  const int deg = end - start;
  float dh = hg == 0 ? denom[0] : hg == 1 ? denom[1] : hg == 2 ? denom[2] : denom[3];
  float inv = deg ? 1.f / dh : 0.f;
  float4 bv = *(const float4*)(b1 + half * 256 + lane * 4);
  float ox = fmaxf(acc.x * inv + bv.x, 0.f);
  float oy = fmaxf(acc.y * inv + bv.y, 0.f);
  float oz = fmaxf(acc.z * inv + bv.z, 0.f);
  float ow = fmaxf(acc.w * inv + bv.w, 0.f);
  __half2 p0 = __floats2half2_rn(ox, oy);
  __half2 p1 = __floats2half2_rn(oz, ow);
  uint2 u;
  u.x = *(unsigned int*)&p0;
  u.y = *(unsigned int*)&p1;
  *(uint2*)(x2 + (size_t)n * 512 + half * 256 + lane * 4) = u;
}

// layer2: 1 head x 64 dims (h2 fp16). Wave per node; stats lane-per-edge;
// gather 4 edges in parallel via 16-lane groups, 8B (4 halves) per lane.
__global__ __launch_bounds__(256) void agg2_k(const __half* __restrict__ h2,
                                              const float* __restrict__ el,
                                              const float* __restrict__ er,
                                              const int* __restrict__ row_ptr,
                                              const int* __restrict__ esrc,
                                              const float* __restrict__ b2,
                                              float* __restrict__ out, int N) {
  __shared__ float p_lds[4][64];
  __shared__ int   s_lds[4][64];
  const int widx = threadIdx.x >> 6;
  const int lane = threadIdx.x & 63;
  const int n = blockIdx.x * 4 + widx;
  if (n >= N) return;
  const int start = row_ptr[n], end = row_ptr[n + 1];
  const int eg = lane >> 4;
  const int dg = lane & 15;
  const float ern = er[n];

  float4 acc = make_float4(0.f, 0.f, 0.f, 0.f);
  float m = -INFINITY, denom = 0.f;

  for (int base = start; base < end; base += 64) {
    int j = base + lane;
    bool valid = j < end;
    int s = valid ? esrc[j] : 0;
    float sc = valid ? lrelu(el[s] + ern) : -INFINITY;
    float bm = wred_max(sc);
    float nm = fmaxf(m, bm);
    float f = expf(m - nm);
    m = nm;
    float p = valid ? expf(sc - nm) : 0.f;
    denom = denom * f + wred_sum(p);
    acc.x *= f; acc.y *= f; acc.z *= f; acc.w *= f;

    p_lds[widx][lane] = p;
    s_lds[widx][lane] = s;

    const int cnt = min(64, end - base);
    for (int jj = 0; jj < cnt; jj += 4) {
      int myj = jj + eg;
      bool v2 = myj < cnt;
      int ss = s_lds[widx][v2 ? myj : 0];
      float a = v2 ? p_lds[widx][myj] : 0.f;
      uint2 hv = *(const uint2*)(h2 + (size_t)ss * 64 + dg * 4);
      float2 f01 = __half22float2(*(__half2*)&hv.x);
      float2 f23 = __half22float2(*(__half2*)&hv.y);
      acc.x = fmaf(a, f01.x, acc.x);
      acc.y = fmaf(a, f01.y, acc.y);
      acc.z = fmaf(a, f23.x, acc.z);
      acc.w = fmaf(a, f23.y, acc.w);
    }
  }

  #pragma unroll
  for (int off = 16; off <= 32; off <<= 1) {
    acc.x += __shfl_xor(acc.x, off);
    acc.y += __shfl_xor(acc.y, off);
    acc.z += __shfl_xor(acc.z, off);
    acc.w += __shfl_xor(acc.w, off);
  }

  if (eg == 0) {
    const int deg = end - start;
    float inv = deg ? 1.f / denom : 0.f;
    float4 bv = *(const float4*)(b2 + dg * 4);
    float4 o;
    o.x = acc.x * inv + bv.x;
    o.y = acc.y * inv + bv.y;
    o.z = acc.z * inv + bv.z;
    o.w = acc.w * inv + bv.w;
    *(float4*)(out + (size_t)n * 64 + dg * 4) = o;
  }
}

// ---------------------------------------------------------------------------

extern "C" void kernel_launch(void* const* d_in, const int* in_sizes, int n_in,
                              void* d_out, int out_size, void* d_ws, size_t ws_size,
                              hipStream_t stream) {
  const float* feats = (const float*)d_in[0];
  const float* W1    = (const float*)d_in[1];
  const float* al1   = (const float*)d_in[2];
  const float* ar1   = (const float*)d_in[3];
  const float* b1    = (const float*)d_in[4];
  const float* W2    = (const float*)d_in[5];
  const float* al2   = (const float*)d_in[6];
  const float* ar2   = (const float*)d_in[7];
  const float* b2    = (const float*)d_in[8];
  const int*   src   = (const int*)d_in[9];
  const int*   dst   = (const int*)d_in[10];

  const int N = in_sizes[0] / 256;   // 50000
  const int E = in_sizes[9];         // 800000
  const int IN = 256, HD1 = 512, D2 = 64;

  char* w = (char*)d_ws;
  size_t off = 0;
  auto alloc = [&](size_t bytes) -> void* {
    void* p = w + off;
    off = (off + bytes + 255) & ~(size_t)255;
    return p;
  };
  __half* h1h    = (__half*)alloc((size_t)N * HD1 * 2);
  __half* x2h    = (__half*)alloc((size_t)N * HD1 * 2);
  __half* h2h    = (__half*)alloc((size_t)N * D2 * 2);
  __half* W1t    = (__half*)alloc((size_t)IN * HD1 * 2);   // [512][256]
  __half* W2t    = (__half*)alloc((size_t)HD1 * D2 * 2);   // [64][512]
  float* el1     = (float*)alloc((size_t)N * 8 * 4);
  float* er1     = (float*)alloc((size_t)N * 8 * 4);
  float* el2     = (float*)alloc((size_t)N * 4);
  float* er2     = (float*)alloc((size_t)N * 4);
  int*   deg     = (int*)alloc((size_t)N * 4);
  int*   row_ptr = (int*)alloc((size_t)(N + 1) * 4);
  int*   pos     = (int*)alloc((size_t)N * 4);
  int*   bsum    = (int*)alloc(64 * 4);
  int*   esrc    = (int*)alloc((size_t)E * 4);

  float* outp = (float*)d_out;

  const int NB_E   = (E + 255) / 256;
  const int NB_N   = (N + 255) / 256;
  const int NB_SC  = (N + 1023) / 1024;
  const int NB_W4  = (N + 3) / 4;
  const int NB_AG1 = (2 * N + 3) / 4;

  // ---- CSR build (dst-sorted src list), shared by both layers
  hipMemsetAsync(deg, 0, (size_t)N * 4, stream);
  hist_k<<<NB_E, 256, 0, stream>>>(dst, deg, E);
  scan_block_k<<<NB_SC, 1024, 0, stream>>>(deg, row_ptr, bsum, N);
  scan_sums_k<<<1, 64, 0, stream>>>(bsum, NB_SC);
  scan_add_k<<<NB_N, 256, 0, stream>>>(row_ptr, bsum, N);
  pos_init_k<<<NB_N, 256, 0, stream>>>(pos, row_ptr, N);
  scatter_k<<<NB_E, 256, 0, stream>>>(src, dst, pos, esrc, E);

  // ---- weight prep (fp16 transposed)
  cvt_t_k<<<(IN * HD1 + 255) / 256, 256, 0, stream>>>(W1, W1t, IN, HD1);
  cvt_t_k<<<(HD1 * D2 + 255) / 256, 256, 0, stream>>>(W2, W2t, HD1, D2);

  // ---- layer 1: MFMA GEMM (feats fp32 -> h1 fp16)
  {
    dim3 g(HD1 / 128, (N + 127) / 128);
    gemm16_k<128, true><<<g, 256, 0, stream>>>(feats, W1t, h1h, N, HD1, IN);
  }
  elr1_k<<<NB_W4, 256, 0, stream>>>(h1h, al1, ar1, el1, er1, N);
  agg1_k<<<NB_AG1, 256, 0, stream>>>(h1h, el1, er1, row_ptr, esrc, b1, x2h, N);

  // ---- layer 2: MFMA GEMM (x2 fp16 -> h2 fp16)
  {
    dim3 g(D2 / 64, (N + 127) / 128);
    gemm16_k<64, false><<<g, 256, 0, stream>>>(x2h, W2t, h2h, N, D2, HD1);
  }
  elr2_k<<<NB_W4, 256, 0, stream>>>(h2h, al2, ar2, el2, er2, N);
  agg2_k<<<NB_W4, 256, 0, stream>>>(h2h, el2, er2, row_ptr, esrc, b2, outp, N);
}